// Round 2
// baseline (865.867 us; speedup 1.0000x reference)
//
#include <hip/hip_runtime.h>

#define PI_F 3.14159265358979323846f

// Problem constants: B=4, Cin=Cout=64, H=W=128, Wf=65, K=3
#define HH 128
#define WW 128
#define WF 65
#define NB 4
#define NC 64
#define CPLX_PER_IMG (HH * WF)                  // 8320
#define R_FLOATS (NB * NC * CPLX_PER_IMG * 2)   // 4,259,840 floats per complex buffer

// ---------------- K1: row-wise real DFT (rfft along W), radix-2 over x ----------------
// Block per (b,c) image. LDS holds image transposed [x][r] (pitch 129, conflict-free).
// Output R layout: [img][v][r] (r contiguous -> coalesced writes, colfft reads rows).
__global__ __launch_bounds__(256) void k_rowfft(const float* __restrict__ x,
                                                float2* __restrict__ R) {
    __shared__ float xs[128 * 129];
    int t = threadIdx.x;
    size_t img = blockIdx.x;
    const float* gx = x + img * 16384;
    for (int k = t; k < 16384; k += 256) {
        int r = k >> 7, xx = k & 127;
        xs[xx * 129 + r] = gx[k];
    }
    __syncthreads();
    int rl = t & 127, vh = t >> 7;
    float2* Rimg = R + img * CPLX_PER_IMG;
    for (int v = vh; v < 64; v += 2) {
        // E(v)=sum_k row[2k] w^k, O(v)=sum_k row[2k+1] w^k, w=e^{-2pi i v/64}
        float ss, cc;
        __sincosf(-2.f * PI_F * (float)v / 64.f, &ss, &cc);
        float stx = cc, sty = ss;
        float wx = 1.f, wy = 0.f;
        float Ex = 0.f, Ey = 0.f, Ox = 0.f, Oy = 0.f;
        for (int k = 0; k < 64; ++k) {
            float a = xs[(2 * k) * 129 + rl];
            float b = xs[(2 * k + 1) * 129 + rl];
            Ex += a * wx; Ey += a * wy;
            Ox += b * wx; Oy += b * wy;
            float nwx = wx * stx - wy * sty;
            wy = wx * sty + wy * stx; wx = nwx;
        }
        float s1, c1;
        __sincosf(-2.f * PI_F * (float)v / 128.f, &s1, &c1);   // W_128^v
        float wox = c1 * Ox - s1 * Oy;
        float woy = c1 * Oy + s1 * Ox;
        Rimg[v * 128 + rl] = make_float2(Ex + wox, Ey + woy);
        if (v == 0)  // bin 64: sum (-1)^x row[x] = E(0) - O(0)
            Rimg[64 * 128 + rl] = make_float2(Ex - Ox, Ey - Oy);
    }
}

// ---------------- K2: column complex DFT + fftshift + high-pass mask, radix-2 ----------------
// Block per image. LDS [v][r]. Thread owns u in {ul, ul+32}; radix-2 emits (u, u+64).
// Output Xs layout: [img][v_out][u_out] (u contiguous -> coalesced, gemm-friendly).
__global__ __launch_bounds__(256) void k_colfft(const float2* __restrict__ R,
                                                float2* __restrict__ Xs) {
    __shared__ float2 cimg[WF * 128];
    int t = threadIdx.x;
    size_t img = blockIdx.x;
    const float2* gR = R + img * CPLX_PER_IMG;
    for (int k = t; k < CPLX_PER_IMG; k += 256) cimg[k] = gR[k];
    __syncthreads();
    int ul = t & 31, v2 = t >> 5;
    float2* Ximg = Xs + img * CPLX_PER_IMG;
    int uA = ul, uB = ul + 32;
    float sA, cA, sB, cB;
    __sincosf(-2.f * PI_F * (float)uA / 64.f, &sA, &cA);
    __sincosf(-2.f * PI_F * (float)uB / 64.f, &sB, &cB);
    float tsA, tcA, tsB, tcB;
    __sincosf(-2.f * PI_F * (float)uA / 128.f, &tsA, &tcA);
    __sincosf(-2.f * PI_F * (float)uB / 128.f, &tsB, &tcB);
    for (int v = v2; v < WF; v += 8) {
        const float2* col = cimg + v * 128;
        float wAx = 1.f, wAy = 0.f, wBx = 1.f, wBy = 0.f;
        float EAx = 0, EAy = 0, OAx = 0, OAy = 0;
        float EBx = 0, EBy = 0, OBx = 0, OBy = 0;
        for (int k = 0; k < 64; ++k) {
            float2 c0 = col[2 * k];
            float2 c1 = col[2 * k + 1];
            EAx += c0.x * wAx - c0.y * wAy;  EAy += c0.x * wAy + c0.y * wAx;
            OAx += c1.x * wAx - c1.y * wAy;  OAy += c1.x * wAy + c1.y * wAx;
            EBx += c0.x * wBx - c0.y * wBy;  EBy += c0.x * wBy + c0.y * wBx;
            OBx += c1.x * wBx - c1.y * wBy;  OBy += c1.x * wBy + c1.y * wBx;
            float nw = wAx * cA - wAy * sA;  wAy = wAx * sA + wAy * cA;  wAx = nw;
            nw = wBx * cB - wBy * sB;        wBy = wBx * sB + wBy * cB;  wBx = nw;
        }
        int v_out = v + 32; if (v_out >= WF) v_out -= WF;
        int dv2 = (v_out - 64) * (v_out - 64);
        float WOx = tcA * OAx - tsA * OAy, WOy = tcA * OAy + tsA * OAx;
        {   // out(uA) -> u_out = uA+64 ; out(uA+64) -> u_out = uA
            int uo = uA + 64; int du = uo - 64;
            bool keep = (du * du + dv2) > 900;
            Ximg[v_out * 128 + uo] = keep ? make_float2(EAx + WOx, EAy + WOy) : make_float2(0.f, 0.f);
            uo = uA; du = uo - 64;
            keep = (du * du + dv2) > 900;
            Ximg[v_out * 128 + uo] = keep ? make_float2(EAx - WOx, EAy - WOy) : make_float2(0.f, 0.f);
        }
        WOx = tcB * OBx - tsB * OBy; WOy = tcB * OBy + tsB * OBx;
        {
            int uo = uB + 64; int du = uo - 64;
            bool keep = (du * du + dv2) > 900;
            Ximg[v_out * 128 + uo] = keep ? make_float2(EBx + WOx, EBy + WOy) : make_float2(0.f, 0.f);
            uo = uB; du = uo - 64;
            keep = (du * du + dv2) > 900;
            Ximg[v_out * 128 + uo] = keep ? make_float2(EBx - WOx, EBy - WOy) : make_float2(0.f, 0.f);
        }
    }
}

// ---------------- K3: Wv[p][v][i][o] = sum_q w[o,i,p,q] e^{-2pi i v q/128} ----------------
// i-major, o contiguous: gemm stages straight copies, reads [i][o..o+] conflict-free.
__global__ void k_wv(const float* __restrict__ w, float2* __restrict__ Wv) {
    int idx = blockIdx.x * blockDim.x + threadIdx.x;
    if (idx >= 3 * WF * NC * NC) return;
    int o = idx & 63;
    int i = (idx >> 6) & 63;
    int pv = idx >> 12;
    int p = pv / WF;
    int v = pv % WF;
    const float* wp = w + ((size_t)o * 64 + i) * 9 + p * 3;
    float re = wp[0], im = 0.f;
#pragma unroll
    for (int q = 1; q <= 2; ++q) {
        int k = (v * q) & 127;
        float s, c;
        __sincosf(-2.f * PI_F * (float)k / 128.f, &s, &c);
        re += wp[q] * c;
        im += wp[q] * s;
    }
    Wv[idx] = make_float2(re, im);
}

// ---------------- K4: per-v GEMM over (i,p) with phase fold ----------------
// Z[b,o,u,v] = sum_p e^{-2pi i u p/128} sum_i Xs[b,i,u,v] * Wv[p,v,i,o]
// Block: (v, 16-u chunk). LDS: Xs tile [b][i][uu] 32 KB + Wp [i][o] 32 KB = 64 KB.
// Thread (b, og, ug) owns o in {og+16a}, u in {u0+ug+4j}: 4x4 register tile.
__global__ __launch_bounds__(256) void k_gemm(const float2* __restrict__ Xs,
                                              const float2* __restrict__ Wvg,
                                              float2* __restrict__ Z) {
    __shared__ float2 XsS[NB * NC * 16];     // [b][i][uu]
    __shared__ float2 Wp[NC * NC];           // [i][o]
    int t = threadIdx.x;
    int v = blockIdx.x >> 3;
    int u0 = (blockIdx.x & 7) * 16;
    for (int k = t; k < 4096; k += 256) {
        int bi = k >> 4, uu = k & 15;
        XsS[k] = Xs[(size_t)bi * CPLX_PER_IMG + v * 128 + u0 + uu];
    }
    int b = t >> 6, og = (t >> 2) & 15, ug = t & 3;
    float accFx[16], accFy[16], accPx[16], accPy[16];
#pragma unroll
    for (int m = 0; m < 16; ++m) { accFx[m] = 0.f; accFy[m] = 0.f; }
    const float2* XsB = XsS + b * NC * 16;
    for (int p = 0; p < 3; ++p) {
        __syncthreads();
        const float2* wg = Wvg + ((size_t)(p * WF + v) << 12);
        for (int k = t; k < 4096; k += 256) Wp[k] = wg[k];
        __syncthreads();
#pragma unroll
        for (int m = 0; m < 16; ++m) { accPx[m] = 0.f; accPy[m] = 0.f; }
#pragma unroll 4
        for (int i = 0; i < NC; ++i) {
            float2 xv[4], wv[4];
#pragma unroll
            for (int j = 0; j < 4; ++j) xv[j] = XsB[i * 16 + ug + 4 * j];
#pragma unroll
            for (int a = 0; a < 4; ++a) wv[a] = Wp[i * 64 + og + 16 * a];
#pragma unroll
            for (int a = 0; a < 4; ++a)
#pragma unroll
                for (int j = 0; j < 4; ++j) {
                    accPx[a * 4 + j] += wv[a].x * xv[j].x - wv[a].y * xv[j].y;
                    accPy[a * 4 + j] += wv[a].x * xv[j].y + wv[a].y * xv[j].x;
                }
        }
        // fold: accF += e^{-2pi i u p/128} * accP
#pragma unroll
        for (int j = 0; j < 4; ++j) {
            int u = u0 + ug + 4 * j;
            float ss, cc;
            __sincosf(-2.f * PI_F * (float)((u * p) & 127) / 128.f, &ss, &cc);
#pragma unroll
            for (int a = 0; a < 4; ++a) {
                accFx[a * 4 + j] += cc * accPx[a * 4 + j] - ss * accPy[a * 4 + j];
                accFy[a * 4 + j] += cc * accPy[a * 4 + j] + ss * accPx[a * 4 + j];
            }
        }
    }
#pragma unroll
    for (int a = 0; a < 4; ++a)
#pragma unroll
        for (int j = 0; j < 4; ++j) {
            int o = og + 16 * a;
            int u = u0 + ug + 4 * j;
            Z[((size_t)(b * 64 + o)) * CPLX_PER_IMG + v * 128 + u] =
                make_float2(accFx[a * 4 + j], accFy[a * 4 + j]);
        }
}

// ---------------- K5: inverse complex DFT along u (in place), radix-2, scale 1/128 ----------
__global__ __launch_bounds__(256) void k_ifftu(float2* __restrict__ Z) {
    __shared__ float2 cimg[WF * 128];
    int t = threadIdx.x;
    size_t img = blockIdx.x;
    float2* gZ = Z + img * CPLX_PER_IMG;
    for (int k = t; k < CPLX_PER_IMG; k += 256) cimg[k] = gZ[k];
    __syncthreads();
    int ul = t & 31, v2 = t >> 5;
    int hA = ul, hB = ul + 32;
    float sA, cA, sB, cB;
    __sincosf(2.f * PI_F * (float)hA / 64.f, &sA, &cA);
    __sincosf(2.f * PI_F * (float)hB / 64.f, &sB, &cB);
    float tsA, tcA, tsB, tcB;
    __sincosf(2.f * PI_F * (float)hA / 128.f, &tsA, &tcA);
    __sincosf(2.f * PI_F * (float)hB / 128.f, &tsB, &tcB);
    const float sc = 1.f / 128.f;
    for (int v = v2; v < WF; v += 8) {
        const float2* col = cimg + v * 128;
        float wAx = 1.f, wAy = 0.f, wBx = 1.f, wBy = 0.f;
        float EAx = 0, EAy = 0, OAx = 0, OAy = 0;
        float EBx = 0, EBy = 0, OBx = 0, OBy = 0;
        for (int k = 0; k < 64; ++k) {
            float2 c0 = col[2 * k];
            float2 c1 = col[2 * k + 1];
            EAx += c0.x * wAx - c0.y * wAy;  EAy += c0.x * wAy + c0.y * wAx;
            OAx += c1.x * wAx - c1.y * wAy;  OAy += c1.x * wAy + c1.y * wAx;
            EBx += c0.x * wBx - c0.y * wBy;  EBy += c0.x * wBy + c0.y * wBx;
            OBx += c1.x * wBx - c1.y * wBy;  OBy += c1.x * wBy + c1.y * wBx;
            float nw = wAx * cA - wAy * sA;  wAy = wAx * sA + wAy * cA;  wAx = nw;
            nw = wBx * cB - wBy * sB;        wBy = wBx * sB + wBy * cB;  wBx = nw;
        }
        float WOx = tcA * OAx - tsA * OAy, WOy = tcA * OAy + tsA * OAx;
        gZ[v * 128 + hA]      = make_float2((EAx + WOx) * sc, (EAy + WOy) * sc);
        gZ[v * 128 + hA + 64] = make_float2((EAx - WOx) * sc, (EAy - WOy) * sc);
        WOx = tcB * OBx - tsB * OBy; WOy = tcB * OBy + tsB * OBx;
        gZ[v * 128 + hB]      = make_float2((EBx + WOx) * sc, (EBy + WOy) * sc);
        gZ[v * 128 + hB + 64] = make_float2((EBx - WOx) * sc, (EBy - WOy) * sc);
    }
}

// ---------------- K6: c2r inverse along v (halfcomplex) + bias ----------------
// Block per image. LDS transposed [h][v] pitch 67. Thread: 4 consecutive x, 16 h rows.
#define IR_PITCH 67
__global__ __launch_bounds__(256) void k_irow(const float2* __restrict__ Zi,
                                              const float* __restrict__ bias,
                                              float* __restrict__ out) {
    __shared__ float2 zi[128 * IR_PITCH];
    int t = threadIdx.x;
    size_t img = blockIdx.x;
    const float2* gZ = Zi + img * CPLX_PER_IMG;
    for (int k = t; k < CPLX_PER_IMG; k += 256) {
        int vv = k >> 7, h = k & 127;
        zi[h * IR_PITCH + vv] = gZ[k];
    }
    __syncthreads();
    float bo = bias[img & 63];
    int xg = t & 31, hb = t >> 5;
    float2 st[4];
#pragma unroll
    for (int j = 0; j < 4; ++j) {
        float ss, cc;
        __sincosf(2.f * PI_F * (float)(xg * 4 + j) / 128.f, &ss, &cc);
        st[j] = make_float2(cc, ss);
    }
    for (int h = hb; h < 128; h += 8) {
        const float2* row = zi + h * IR_PITCH;
        float acc[4] = {0.f, 0.f, 0.f, 0.f};
        float wx[4] = {1.f, 1.f, 1.f, 1.f}, wy[4] = {0.f, 0.f, 0.f, 0.f};
        for (int vv = 0; vv <= 64; ++vv) {
            float2 z = row[vv];
#pragma unroll
            for (int j = 0; j < 4; ++j) {
                acc[j] += 2.f * (z.x * wx[j] - z.y * wy[j]);
                float nw = wx[j] * st[j].x - wy[j] * st[j].y;
                wy[j] = wx[j] * st[j].y + wy[j] * st[j].x; wx[j] = nw;
            }
        }
        float z0 = row[0].x;
        float z64 = row[64].x;
        const float sc = 1.f / 128.f;
        float4 res;
        res.x = (acc[0] - z0 - z64) * sc + bo;   // x even: subtract +z64
        res.y = (acc[1] - z0 + z64) * sc + bo;   // x odd:  subtract -z64
        res.z = (acc[2] - z0 - z64) * sc + bo;
        res.w = (acc[3] - z0 + z64) * sc + bo;
        *(float4*)&out[img * 16384 + h * 128 + xg * 4] = res;
    }
}

extern "C" void kernel_launch(void* const* d_in, const int* in_sizes, int n_in,
                              void* d_out, int out_size, void* d_ws, size_t ws_size,
                              hipStream_t stream) {
    const float* x = (const float*)d_in[0];      // [4,64,128,128]
    const float* w = (const float*)d_in[1];      // [64,64,3,3]
    const float* bias = (const float*)d_in[2];   // [64]
    float* out = (float*)d_out;                  // [4,64,128,128]

    float* ws = (float*)d_ws;
    float2* R  = (float2*)ws;                        // 17 MB; reused as Z then Zi
    float2* Xs = (float2*)(ws + R_FLOATS);           // 17 MB
    float2* Wv = (float2*)(ws + 2 * R_FLOATS);       // 6.4 MB

    k_rowfft<<<NB * NC, 256, 0, stream>>>(x, R);
    k_colfft<<<NB * NC, 256, 0, stream>>>(R, Xs);
    k_wv<<<(3 * WF * NC * NC + 255) / 256, 256, 0, stream>>>(w, Wv);
    k_gemm<<<WF * 8, 256, 0, stream>>>(Xs, Wv, R);   // R now holds Z
    k_ifftu<<<NB * NC, 256, 0, stream>>>(R);
    k_irow<<<NB * NC, 256, 0, stream>>>(R, bias, out);
}

// Round 3
// 283.155 us; speedup vs baseline: 3.0579x; 3.0579x over previous
//
#include <hip/hip_runtime.h>

#define PI_F 3.14159265358979323846f

// Problem constants: B=4, Cin=Cout=64, H=W=128, Wf=65, K=3
#define HH 128
#define WW 128
#define WF 65
#define NB 4
#define NC 64
#define CPLX_PER_IMG (HH * WF)                  // 8320
#define R_FLOATS (NB * NC * CPLX_PER_IMG * 2)   // 4,259,840 floats per complex buffer

// ---------------- K1: row-wise real DFT (rfft along W) ----------------
// grid = (img, 32-row chunk) = 256*4. LDS: image chunk transposed [x][r] pitch 33 + tw table.
// Each thread owns (r, vb) and accumulates 8 bins v = vb+8p in one 128-iteration loop.
// Output R layout: [img][v][r] (r contiguous).
__global__ __launch_bounds__(256) void k_rowfft(const float* __restrict__ x,
                                                float2* __restrict__ R) {
    __shared__ float xs[128 * 33];
    __shared__ __align__(16) float2 tw[128];
    int t = threadIdx.x;
    int img = blockIdx.x >> 2;
    int r0 = (blockIdx.x & 3) * 32;
    const float* gx = x + (size_t)img * 16384 + (size_t)r0 * 128;
    for (int k = t; k < 4096; k += 256) {
        int rl = k >> 7, xx = k & 127;
        xs[xx * 33 + rl] = gx[k];
    }
    if (t < 128) {
        float s, c;
        __sincosf(-2.f * PI_F * (float)t / 128.f, &s, &c);
        tw[t] = make_float2(c, s);
    }
    __syncthreads();
    int r = t & 31, vb = t >> 5;             // vb in [0,8)
    float2* Rimg = R + (size_t)img * CPLX_PER_IMG;
    float rex[8], imx[8];
    int idx[8];
#pragma unroll
    for (int p = 0; p < 8; ++p) { rex[p] = 0.f; imx[p] = 0.f; idx[p] = 0; }
#pragma unroll 2
    for (int xx = 0; xx < 128; ++xx) {
        float a = xs[xx * 33 + r];
#pragma unroll
        for (int p = 0; p < 8; ++p) {
            float2 w = tw[idx[p]];
            rex[p] += a * w.x;
            imx[p] += a * w.y;
            idx[p] = (idx[p] + vb + 8 * p) & 127;
        }
    }
#pragma unroll
    for (int p = 0; p < 8; ++p) {
        int v = vb + 8 * p;
        Rimg[v * 128 + r0 + r] = make_float2(rex[p], imx[p]);
    }
    if (t < 32) {                            // bin 64: alternating sum
        float re = 0.f;
#pragma unroll 4
        for (int xx = 0; xx < 128; ++xx) {
            float a = xs[xx * 33 + t];
            re += (xx & 1) ? -a : a;
        }
        Rimg[64 * 128 + r0 + t] = make_float2(re, 0.f);
    }
}

// ---------------- K2: column complex DFT + fftshift + high-pass mask, radix-2 ----------------
// grid = (img, 16-v chunk) = 256*5. Thread: u = t&63, vg = t>>6; handles 4 columns, emits
// bins u and u+64 each. Data reads are wave-uniform broadcasts; twiddle is a register recurrence.
// Output Xs layout: [img][v_out][u_out].
__global__ __launch_bounds__(256) void k_colfft(const float2* __restrict__ R,
                                                float2* __restrict__ Xs) {
    __shared__ __align__(16) float2 col[16 * 128];
    int t = threadIdx.x;
    int img = blockIdx.x / 5;
    int vc = blockIdx.x % 5;
    int v0 = vc * 16;
    const float2* gR = R + (size_t)img * CPLX_PER_IMG;
    for (int k = t; k < 2048; k += 256) {
        int vj = k >> 7, h = k & 127;
        int v = v0 + vj;
        col[k] = (v < WF) ? gR[v * 128 + h] : make_float2(0.f, 0.f);
    }
    __syncthreads();
    int u = t & 63, vg = t >> 6;
    float ss, cc, ts, tc;
    __sincosf(-2.f * PI_F * (float)u / 64.f, &ss, &cc);    // E/O step
    __sincosf(-2.f * PI_F * (float)u / 128.f, &ts, &tc);   // final twiddle
    float wx = 1.f, wy = 0.f;
    float Ex[4], Ey[4], Ox[4], Oy[4];
#pragma unroll
    for (int j = 0; j < 4; ++j) { Ex[j] = Ey[j] = Ox[j] = Oy[j] = 0.f; }
    const float4* c4 = (const float4*)col;
#pragma unroll 2
    for (int k = 0; k < 64; ++k) {
#pragma unroll
        for (int j = 0; j < 4; ++j) {
            float4 c01 = c4[(vg * 4 + j) * 64 + k];        // col[2k], col[2k+1]
            Ex[j] += c01.x * wx - c01.y * wy;  Ey[j] += c01.x * wy + c01.y * wx;
            Ox[j] += c01.z * wx - c01.w * wy;  Oy[j] += c01.z * wy + c01.w * wx;
        }
        float nw = wx * cc - wy * ss;
        wy = wx * ss + wy * cc; wx = nw;
    }
    float2* Ximg = Xs + (size_t)img * CPLX_PER_IMG;
#pragma unroll
    for (int j = 0; j < 4; ++j) {
        int v = v0 + vg * 4 + j;
        if (v < WF) {
            float WOx = tc * Ox[j] - ts * Oy[j];
            float WOy = tc * Oy[j] + ts * Ox[j];
            int v_out = v + 32; if (v_out >= WF) v_out -= WF;
            int dv2 = (v_out - 64) * (v_out - 64);
            // bin u -> u_out = u+64 (du = u); bin u+64 -> u_out = u (du = u-64)
            bool keep1 = (u * u + dv2) > 900;
            Ximg[v_out * 128 + u + 64] = keep1 ? make_float2(Ex[j] + WOx, Ey[j] + WOy)
                                               : make_float2(0.f, 0.f);
            int du = u - 64;
            bool keep2 = (du * du + dv2) > 900;
            Ximg[v_out * 128 + u] = keep2 ? make_float2(Ex[j] - WOx, Ey[j] - WOy)
                                          : make_float2(0.f, 0.f);
        }
    }
}

// ---------------- K3: Wv[p][v][i][o] = sum_q w[o,i,p,q] e^{-2pi i v q/128} ----------------
__global__ void k_wv(const float* __restrict__ w, float2* __restrict__ Wv) {
    int idx = blockIdx.x * blockDim.x + threadIdx.x;
    if (idx >= 3 * WF * NC * NC) return;
    int o = idx & 63;
    int i = (idx >> 6) & 63;
    int pv = idx >> 12;
    int p = pv / WF;
    int v = pv % WF;
    const float* wp = w + ((size_t)o * 64 + i) * 9 + p * 3;
    float re = wp[0], im = 0.f;
#pragma unroll
    for (int q = 1; q <= 2; ++q) {
        int k = (v * q) & 127;
        float s, c;
        __sincosf(-2.f * PI_F * (float)k / 128.f, &s, &c);
        re += wp[q] * c;
        im += wp[q] * s;
    }
    Wv[idx] = make_float2(re, im);
}

// ---------------- K4: per-v GEMM over (i,p) with phase fold ----------------
// Z[b,o,u,v] = sum_p e^{-2pi i u p/128} sum_i Xs[b,i,u,v] * Wv[p,v,i,o]
__global__ __launch_bounds__(256) void k_gemm(const float2* __restrict__ Xs,
                                              const float2* __restrict__ Wvg,
                                              float2* __restrict__ Z) {
    __shared__ __align__(16) float2 XsS[NB * NC * 16];   // [b][i][uu] 32 KB
    __shared__ __align__(16) float2 Wp[NC * NC];         // [i][o]     32 KB
    int t = threadIdx.x;
    int v = blockIdx.x >> 3;
    int u0 = (blockIdx.x & 7) * 16;
    {
        const float4* gX4 = (const float4*)Xs;
        float4* XsS4 = (float4*)XsS;
        for (int k = t; k < 2048; k += 256) {
            int bi = k >> 3, uu = k & 7;
            XsS4[bi * 8 + uu] = gX4[(size_t)bi * 4160 + v * 64 + (u0 >> 1) + uu];
        }
    }
    int b = t >> 6, og = (t >> 2) & 15, ug = t & 3;
    float accFx[16], accFy[16], accPx[16], accPy[16];
#pragma unroll
    for (int m = 0; m < 16; ++m) { accFx[m] = 0.f; accFy[m] = 0.f; }
    const float2* XsB = XsS + b * NC * 16;
    for (int p = 0; p < 3; ++p) {
        __syncthreads();
        const float4* wg4 = (const float4*)(Wvg + ((size_t)(p * WF + v) << 12));
        float4* Wp4 = (float4*)Wp;
        for (int k = t; k < 2048; k += 256) Wp4[k] = wg4[k];
        __syncthreads();
#pragma unroll
        for (int m = 0; m < 16; ++m) { accPx[m] = 0.f; accPy[m] = 0.f; }
#pragma unroll 4
        for (int i = 0; i < NC; ++i) {
            float2 xv[4], wv[4];
#pragma unroll
            for (int j = 0; j < 4; ++j) xv[j] = XsB[i * 16 + ug + 4 * j];
#pragma unroll
            for (int a = 0; a < 4; ++a) wv[a] = Wp[i * 64 + og + 16 * a];
#pragma unroll
            for (int a = 0; a < 4; ++a)
#pragma unroll
                for (int j = 0; j < 4; ++j) {
                    accPx[a * 4 + j] += wv[a].x * xv[j].x - wv[a].y * xv[j].y;
                    accPy[a * 4 + j] += wv[a].x * xv[j].y + wv[a].y * xv[j].x;
                }
        }
#pragma unroll
        for (int j = 0; j < 4; ++j) {
            int u = u0 + ug + 4 * j;
            float ss, cc;
            __sincosf(-2.f * PI_F * (float)((u * p) & 127) / 128.f, &ss, &cc);
#pragma unroll
            for (int a = 0; a < 4; ++a) {
                accFx[a * 4 + j] += cc * accPx[a * 4 + j] - ss * accPy[a * 4 + j];
                accFy[a * 4 + j] += cc * accPy[a * 4 + j] + ss * accPx[a * 4 + j];
            }
        }
    }
#pragma unroll
    for (int a = 0; a < 4; ++a)
#pragma unroll
        for (int j = 0; j < 4; ++j) {
            int o = og + 16 * a;
            int u = u0 + ug + 4 * j;
            Z[((size_t)(b * 64 + o)) * CPLX_PER_IMG + v * 128 + u] =
                make_float2(accFx[a * 4 + j], accFy[a * 4 + j]);
        }
}

// ---------------- K5: inverse complex DFT along u (in place), radix-2, scale 1/128 --------
// Same structure as K2, inverse sign, no shift/mask. Layout stays [img][v][h].
__global__ __launch_bounds__(256) void k_ifftu(float2* __restrict__ Z) {
    __shared__ __align__(16) float2 col[16 * 128];
    int t = threadIdx.x;
    int img = blockIdx.x / 5;
    int vc = blockIdx.x % 5;
    int v0 = vc * 16;
    float2* gZ = Z + (size_t)img * CPLX_PER_IMG;
    for (int k = t; k < 2048; k += 256) {
        int vj = k >> 7, u = k & 127;
        int v = v0 + vj;
        col[k] = (v < WF) ? gZ[v * 128 + u] : make_float2(0.f, 0.f);
    }
    __syncthreads();
    int h = t & 63, vg = t >> 6;
    float ss, cc, ts, tc;
    __sincosf(2.f * PI_F * (float)h / 64.f, &ss, &cc);
    __sincosf(2.f * PI_F * (float)h / 128.f, &ts, &tc);
    float wx = 1.f, wy = 0.f;
    float Ex[4], Ey[4], Ox[4], Oy[4];
#pragma unroll
    for (int j = 0; j < 4; ++j) { Ex[j] = Ey[j] = Ox[j] = Oy[j] = 0.f; }
    const float4* c4 = (const float4*)col;
#pragma unroll 2
    for (int k = 0; k < 64; ++k) {
#pragma unroll
        for (int j = 0; j < 4; ++j) {
            float4 c01 = c4[(vg * 4 + j) * 64 + k];
            Ex[j] += c01.x * wx - c01.y * wy;  Ey[j] += c01.x * wy + c01.y * wx;
            Ox[j] += c01.z * wx - c01.w * wy;  Oy[j] += c01.z * wy + c01.w * wx;
        }
        float nw = wx * cc - wy * ss;
        wy = wx * ss + wy * cc; wx = nw;
    }
    const float sc = 1.f / 128.f;
#pragma unroll
    for (int j = 0; j < 4; ++j) {
        int v = v0 + vg * 4 + j;
        if (v < WF) {
            float WOx = tc * Ox[j] - ts * Oy[j];
            float WOy = tc * Oy[j] + ts * Ox[j];
            gZ[v * 128 + h]      = make_float2((Ex[j] + WOx) * sc, (Ey[j] + WOy) * sc);
            gZ[v * 128 + h + 64] = make_float2((Ex[j] - WOx) * sc, (Ey[j] - WOy) * sc);
        }
    }
}

// ---------------- K6: c2r inverse along v (halfcomplex) + bias ----------------
// grid = (img, 16-h chunk) = 256*8. LDS transposed [j][v] pitch 66. Thread: xh = t&63,
// jb = t>>6; handles 4 h rows and outputs x = xh and xh+64 (parity pairing).
#define K6P 66
__global__ __launch_bounds__(256) void k_irow(const float2* __restrict__ Zi,
                                              const float* __restrict__ bias,
                                              float* __restrict__ out) {
    __shared__ __align__(16) float2 zi[16 * K6P];
    int t = threadIdx.x;
    int img = blockIdx.x >> 3;
    int h0 = (blockIdx.x & 7) * 16;
    const float2* gZ = Zi + (size_t)img * CPLX_PER_IMG;
    for (int k = t; k < 16 * WF; k += 256) {
        int v = k >> 4, j = k & 15;
        zi[j * K6P + v] = gZ[v * 128 + h0 + j];
    }
    __syncthreads();
    int xh = t & 63, jb = t >> 6;
    float bo = bias[img & 63];
    float s1, c1, s2, c2;
    __sincosf(2.f * PI_F * (float)xh / 128.f, &s1, &c1);       // w at v=1
    __sincosf(2.f * PI_F * (float)(2 * xh) / 128.f, &s2, &c2); // step by 2 in v
    float accP[4], accM[4];
#pragma unroll
    for (int j = 0; j < 4; ++j) { accP[j] = 0.f; accM[j] = 0.f; }
    float wex = 1.f, wey = 0.f;      // even chain, at v=0
    float wox = c1, woy = s1;        // odd chain, at v=1
#pragma unroll 2
    for (int m = 0; m < 32; ++m) {
#pragma unroll
        for (int j = 0; j < 4; ++j) {
            float4 z2 = *(const float4*)&zi[(jb + 4 * j) * K6P + 2 * m];  // v=2m, 2m+1
            accP[j] += z2.x * wex - z2.y * wey;
            accM[j] += z2.z * wox - z2.w * woy;
        }
        float nw = wex * c2 - wey * s2;
        wey = wex * s2 + wey * c2; wex = nw;
        nw = wox * c2 - woy * s2;
        woy = wox * s2 + woy * c2; wox = nw;
    }
    float pm = (xh & 1) ? -1.f : 1.f;
    const float sc = 1.f / 128.f;
    float* gout = out + (size_t)img * 16384;
#pragma unroll
    for (int j = 0; j < 4; ++j) {
        int jr = jb + 4 * j;
        float z0v = zi[jr * K6P + 0].x;
        float z64v = zi[jr * K6P + 64].x;
        float base = -z0v + pm * z64v;
        // even chain ended exactly at v=64 term? loop covered v=0..63; add v=64 (real) via pm
        // accP got v=0,2,..,62; accM v=1,3,..,63; v=64 term = pm * z64v, counted ONCE:
        float outA = (2.f * (accP[j] + accM[j]) + pm * z64v + base + z0v - z0v);
        // simplify: out(x) = 2*(accP+accM) - z0 + pm*z64  -> but v=64 term must ALSO appear
        // doubled inside the 2*sum per derivation with correction... use verified closed form:
        outA = (2.f * (accP[j] + accM[j]) + 2.f * pm * z64v - z0v - pm * z64v) * sc + bo;
        float outB = (2.f * (accP[j] - accM[j]) + 2.f * pm * z64v - z0v - pm * z64v) * sc + bo;
        gout[(h0 + jr) * 128 + xh] = outA;
        gout[(h0 + jr) * 128 + xh + 64] = outB;
    }
}

extern "C" void kernel_launch(void* const* d_in, const int* in_sizes, int n_in,
                              void* d_out, int out_size, void* d_ws, size_t ws_size,
                              hipStream_t stream) {
    const float* x = (const float*)d_in[0];      // [4,64,128,128]
    const float* w = (const float*)d_in[1];      // [64,64,3,3]
    const float* bias = (const float*)d_in[2];   // [64]
    float* out = (float*)d_out;                  // [4,64,128,128]

    float* ws = (float*)d_ws;
    float2* R  = (float2*)ws;                        // reused as Z then Zi
    float2* Xs = (float2*)(ws + R_FLOATS);
    float2* Wv = (float2*)(ws + 2 * R_FLOATS);

    k_rowfft<<<NB * NC * 4, 256, 0, stream>>>(x, R);
    k_colfft<<<NB * NC * 5, 256, 0, stream>>>(R, Xs);
    k_wv<<<(3 * WF * NC * NC + 255) / 256, 256, 0, stream>>>(w, Wv);
    k_gemm<<<WF * 8, 256, 0, stream>>>(Xs, Wv, R);   // R now holds Z
    k_ifftu<<<NB * NC * 5, 256, 0, stream>>>(R);
    k_irow<<<NB * NC * 8, 256, 0, stream>>>(R, bias, out);
}

// Round 4
// 157.188 us; speedup vs baseline: 5.5085x; 1.8014x over previous
//
#include <hip/hip_runtime.h>

#define PI_F 3.14159265358979323846f

// Problem constants: B=4, Cin=Cout=64, H=W=128, Wf=65, K=3
#define HH 128
#define WW 128
#define WF 65
#define NB 4
#define NC 64
#define CPLX_PER_IMG (HH * WF)                  // 8320
#define R_FLOATS (NB * NC * CPLX_PER_IMG * 2)   // 4,259,840 floats (17 MB)

typedef __attribute__((ext_vector_type(8))) short short8;
typedef __attribute__((ext_vector_type(4))) float f32x4;

__device__ __forceinline__ ushort f2b(float f) {   // f32 -> bf16 RNE
    unsigned u = __float_as_uint(f);
    u += 0x7fffu + ((u >> 16) & 1u);
    return (ushort)(u >> 16);
}

// ---------------- K1: row-wise real DFT (rfft along W) ----------------
__global__ __launch_bounds__(256) void k_rowfft(const float* __restrict__ x,
                                                float2* __restrict__ R) {
    __shared__ float xs[128 * 33];
    __shared__ __align__(16) float2 tw[128];
    int t = threadIdx.x;
    int img = blockIdx.x >> 2;
    int r0 = (blockIdx.x & 3) * 32;
    const float* gx = x + (size_t)img * 16384 + (size_t)r0 * 128;
    for (int k = t; k < 4096; k += 256) {
        int rl = k >> 7, xx = k & 127;
        xs[xx * 33 + rl] = gx[k];
    }
    if (t < 128) {
        float s, c;
        __sincosf(-2.f * PI_F * (float)t / 128.f, &s, &c);
        tw[t] = make_float2(c, s);
    }
    __syncthreads();
    int r = t & 31, vb = t >> 5;
    float2* Rimg = R + (size_t)img * CPLX_PER_IMG;
    float rex[8], imx[8];
    int idx[8];
#pragma unroll
    for (int p = 0; p < 8; ++p) { rex[p] = 0.f; imx[p] = 0.f; idx[p] = 0; }
#pragma unroll 2
    for (int xx = 0; xx < 128; ++xx) {
        float a = xs[xx * 33 + r];
#pragma unroll
        for (int p = 0; p < 8; ++p) {
            float2 w = tw[idx[p]];
            rex[p] += a * w.x;
            imx[p] += a * w.y;
            idx[p] = (idx[p] + vb + 8 * p) & 127;
        }
    }
#pragma unroll
    for (int p = 0; p < 8; ++p) {
        int v = vb + 8 * p;
        Rimg[v * 128 + r0 + r] = make_float2(rex[p], imx[p]);
    }
    if (t < 32) {
        float re = 0.f;
#pragma unroll 4
        for (int xx = 0; xx < 128; ++xx) {
            float a = xs[xx * 33 + t];
            re += (xx & 1) ? -a : a;
        }
        Rimg[64 * 128 + r0 + t] = make_float2(re, 0.f);
    }
}

// ---------------- K2: column DFT + fftshift + high-pass mask -> bf16 planes ----------------
// Output: XsRe/XsIm [img][v_out][u_out] bf16 (shifted, masked).
__global__ __launch_bounds__(256) void k_colfft(const float2* __restrict__ R,
                                                ushort* __restrict__ XsRe,
                                                ushort* __restrict__ XsIm) {
    __shared__ __align__(16) float2 col[16 * 128];
    int t = threadIdx.x;
    int img = blockIdx.x / 5;
    int vc = blockIdx.x % 5;
    int v0 = vc * 16;
    const float2* gR = R + (size_t)img * CPLX_PER_IMG;
    for (int k = t; k < 2048; k += 256) {
        int vj = k >> 7, h = k & 127;
        int v = v0 + vj;
        col[k] = (v < WF) ? gR[v * 128 + h] : make_float2(0.f, 0.f);
    }
    __syncthreads();
    int u = t & 63, vg = t >> 6;
    float ss, cc, ts, tc;
    __sincosf(-2.f * PI_F * (float)u / 64.f, &ss, &cc);
    __sincosf(-2.f * PI_F * (float)u / 128.f, &ts, &tc);
    float wx = 1.f, wy = 0.f;
    float Ex[4], Ey[4], Ox[4], Oy[4];
#pragma unroll
    for (int j = 0; j < 4; ++j) { Ex[j] = Ey[j] = Ox[j] = Oy[j] = 0.f; }
    const float4* c4 = (const float4*)col;
#pragma unroll 2
    for (int k = 0; k < 64; ++k) {
#pragma unroll
        for (int j = 0; j < 4; ++j) {
            float4 c01 = c4[(vg * 4 + j) * 64 + k];
            Ex[j] += c01.x * wx - c01.y * wy;  Ey[j] += c01.x * wy + c01.y * wx;
            Ox[j] += c01.z * wx - c01.w * wy;  Oy[j] += c01.z * wy + c01.w * wx;
        }
        float nw = wx * cc - wy * ss;
        wy = wx * ss + wy * cc; wx = nw;
    }
    ushort* pXr = XsRe + (size_t)img * CPLX_PER_IMG;
    ushort* pXi = XsIm + (size_t)img * CPLX_PER_IMG;
#pragma unroll
    for (int j = 0; j < 4; ++j) {
        int v = v0 + vg * 4 + j;
        if (v < WF) {
            float WOx = tc * Ox[j] - ts * Oy[j];
            float WOy = tc * Oy[j] + ts * Ox[j];
            int v_out = v + 32; if (v_out >= WF) v_out -= WF;
            int dv2 = (v_out - 64) * (v_out - 64);
            bool keep1 = (u * u + dv2) > 900;                 // bin u -> u_out = u+64
            int du = u - 64;
            bool keep2 = (du * du + dv2) > 900;               // bin u+64 -> u_out = u
            int o1 = v_out * 128 + u + 64;
            int o2 = v_out * 128 + u;
            pXr[o1] = keep1 ? f2b(Ex[j] + WOx) : 0;
            pXi[o1] = keep1 ? f2b(Ey[j] + WOy) : 0;
            pXr[o2] = keep2 ? f2b(Ex[j] - WOx) : 0;
            pXi[o2] = keep2 ? f2b(Ey[j] - WOy) : 0;
        }
    }
}

// ---------------- K3: Wv planes [p][v][o][i] bf16: sum_q w[o,i,p,q] e^{-2pi i v q/128} ------
__global__ void k_wv(const float* __restrict__ w,
                     ushort* __restrict__ WvRe, ushort* __restrict__ WvIm) {
    int x = blockIdx.x * 256 + threadIdx.x;
    if (x >= 3 * WF * NC * NC) return;
    int i = x & 63;
    int o = (x >> 6) & 63;
    int pv = x >> 12;
    int p = pv / WF;
    int v = pv % WF;
    const float* wp = w + ((size_t)o * 64 + i) * 9 + p * 3;
    float re = wp[0], im = 0.f;
#pragma unroll
    for (int q = 1; q <= 2; ++q) {
        int k = (v * q) & 127;
        float s, c;
        __sincosf(-2.f * PI_F * (float)k / 128.f, &s, &c);
        re += wp[q] * c;
        im += wp[q] * s;
    }
    WvRe[x] = f2b(re);
    WvIm[x] = f2b(im);
}

// ---------------- K4: per-(v,b) complex GEMM via bf16 MFMA + phase fold ----------------
// Z[b,o,u,v] = sum_p e^{-2pi i u p/128} sum_i Wv[p,v,o,i] * X[b,i,v,u]
// A = W[o][i] (M=o=64), B = X[i][u] (N=u=128), K = i = 64 per p.
// Wave w owns u-tiles {w*32, w*32+16} x all 4 o-tiles; 8 complex acc tile-pairs.
#define AP 72   // LDS pitch in bf16 elems (144 B: 16B-aligned rows, 2-way max conflicts)
__global__ __launch_bounds__(256, 2) void k_gemm(const ushort* __restrict__ XsRe,
                                                 const ushort* __restrict__ XsIm,
                                                 const ushort* __restrict__ WvRe,
                                                 const ushort* __restrict__ WvIm,
                                                 float2* __restrict__ Z) {
    __shared__ ushort XTre[128 * AP], XTim[128 * AP];   // [u][i] 18.4 KB each
    __shared__ ushort WSre[64 * AP],  WSim[64 * AP];    // [o][i]  9.2 KB each
    int t = threadIdx.x;
    int v = blockIdx.x >> 2;
    int b = blockIdx.x & 3;

    // ---- stage X transposed: [u][i], bf16 (reads coalesced over u) ----
    {
        int u = t & 127, qh = t >> 7;
#pragma unroll
        for (int q8 = 0; q8 < 8; ++q8) {
            int q = qh * 8 + q8;
            ushort re4[4], im4[4];
#pragma unroll
            for (int c = 0; c < 4; ++c) {
                int i = q * 4 + c;
                size_t off = ((size_t)(b * 64 + i) * WF + v) * 128 + u;
                re4[c] = XsRe[off];
                im4[c] = XsIm[off];
            }
            *(ushort4*)&XTre[u * AP + q * 4] = make_ushort4(re4[0], re4[1], re4[2], re4[3]);
            *(ushort4*)&XTim[u * AP + q * 4] = make_ushort4(im4[0], im4[1], im4[2], im4[3]);
        }
    }

    int lane = t & 63, wave = t >> 6;
    int lrow = lane & 15, lq = lane >> 4;
    int u0 = wave * 32;

    f32x4 fRe[8], fIm[8];
#pragma unroll
    for (int m = 0; m < 8; ++m) {
        fRe[m] = (f32x4){0.f, 0.f, 0.f, 0.f};
        fIm[m] = (f32x4){0.f, 0.f, 0.f, 0.f};
    }

    for (int p = 0; p < 3; ++p) {
        if (p) __syncthreads();                  // protect W LDS from prev readers
        {   // stage W_p: straight copy, [o][i] padded
            const ushort* gr = WvRe + ((size_t)(p * WF + v)) * 4096;
            const ushort* gi = WvIm + ((size_t)(p * WF + v)) * 4096;
#pragma unroll
            for (int cc = 0; cc < 2; ++cc) {
                int c = t + cc * 256;            // 512 chunks of 8 elems
                int o = c >> 3, i0 = (c & 7) * 8;
                *(short8*)&WSre[o * AP + i0] = *(const short8*)&gr[c * 8];
                *(short8*)&WSim[o * AP + i0] = *(const short8*)&gi[c * 8];
            }
        }
        __syncthreads();                         // covers X staging too (p==0)

        f32x4 pRe[8], pIm[8];
#pragma unroll
        for (int m = 0; m < 8; ++m) {
            pRe[m] = (f32x4){0.f, 0.f, 0.f, 0.f};
            pIm[m] = (f32x4){0.f, 0.f, 0.f, 0.f};
        }
#pragma unroll
        for (int ks = 0; ks < 2; ++ks) {
            int kb = ks * 32 + lq * 8;           // i base for this lane
            short8 br[2], bi[2], bin[2];
#pragma unroll
            for (int ut = 0; ut < 2; ++ut) {
                int u = u0 + ut * 16 + lrow;
                br[ut] = *(const short8*)&XTre[u * AP + kb];
                bi[ut] = *(const short8*)&XTim[u * AP + kb];
                bin[ut] = bi[ut] ^ (short)0x8000;
            }
#pragma unroll
            for (int ot = 0; ot < 4; ++ot) {
                int o = ot * 16 + lrow;
                short8 ar = *(const short8*)&WSre[o * AP + kb];
                short8 ai = *(const short8*)&WSim[o * AP + kb];
#pragma unroll
                for (int ut = 0; ut < 2; ++ut) {
                    int m = ot * 2 + ut;
                    // Re: Ar*Br + Ai*(-Bi); Im: Ar*Bi + Ai*Br
                    pRe[m] = __builtin_amdgcn_mfma_f32_16x16x32_bf16(ai, bin[ut], pRe[m], 0, 0, 0);
                    pRe[m] = __builtin_amdgcn_mfma_f32_16x16x32_bf16(ar, br[ut],  pRe[m], 0, 0, 0);
                    pIm[m] = __builtin_amdgcn_mfma_f32_16x16x32_bf16(ai, br[ut],  pIm[m], 0, 0, 0);
                    pIm[m] = __builtin_amdgcn_mfma_f32_16x16x32_bf16(ar, bi[ut],  pIm[m], 0, 0, 0);
                }
            }
        }
        // phase fold: accF += e^{-2pi i u p/128} * accP   (u = col = lane&15 per tile)
#pragma unroll
        for (int ut = 0; ut < 2; ++ut) {
            int u = u0 + ut * 16 + lrow;
            float sn, cn;
            __sincosf(-2.f * PI_F * (float)(u * p) / 128.f, &sn, &cn);
#pragma unroll
            for (int ot = 0; ot < 4; ++ot) {
                int m = ot * 2 + ut;
#pragma unroll
                for (int e = 0; e < 4; ++e) {
                    fRe[m][e] += pRe[m][e] * cn - pIm[m][e] * sn;
                    fIm[m][e] += pIm[m][e] * cn + pRe[m][e] * sn;
                }
            }
        }
    }

    // ---- write Z[b,o,u,v]: lane holds col u = lane&15(+tile), rows o = lq*4+e ----
#pragma unroll
    for (int ot = 0; ot < 4; ++ot)
#pragma unroll
        for (int ut = 0; ut < 2; ++ut) {
            int m = ot * 2 + ut;
            int u = u0 + ut * 16 + lrow;
#pragma unroll
            for (int e = 0; e < 4; ++e) {
                int o = ot * 16 + lq * 4 + e;
                Z[((size_t)(b * 64 + o)) * CPLX_PER_IMG + v * 128 + u] =
                    make_float2(fRe[m][e], fIm[m][e]);
            }
        }
}

// ---------------- K5: inverse complex DFT along u (in place), radix-2, scale 1/128 --------
__global__ __launch_bounds__(256) void k_ifftu(float2* __restrict__ Z) {
    __shared__ __align__(16) float2 col[16 * 128];
    int t = threadIdx.x;
    int img = blockIdx.x / 5;
    int vc = blockIdx.x % 5;
    int v0 = vc * 16;
    float2* gZ = Z + (size_t)img * CPLX_PER_IMG;
    for (int k = t; k < 2048; k += 256) {
        int vj = k >> 7, u = k & 127;
        int v = v0 + vj;
        col[k] = (v < WF) ? gZ[v * 128 + u] : make_float2(0.f, 0.f);
    }
    __syncthreads();
    int h = t & 63, vg = t >> 6;
    float ss, cc, ts, tc;
    __sincosf(2.f * PI_F * (float)h / 64.f, &ss, &cc);
    __sincosf(2.f * PI_F * (float)h / 128.f, &ts, &tc);
    float wx = 1.f, wy = 0.f;
    float Ex[4], Ey[4], Ox[4], Oy[4];
#pragma unroll
    for (int j = 0; j < 4; ++j) { Ex[j] = Ey[j] = Ox[j] = Oy[j] = 0.f; }
    const float4* c4 = (const float4*)col;
#pragma unroll 2
    for (int k = 0; k < 64; ++k) {
#pragma unroll
        for (int j = 0; j < 4; ++j) {
            float4 c01 = c4[(vg * 4 + j) * 64 + k];
            Ex[j] += c01.x * wx - c01.y * wy;  Ey[j] += c01.x * wy + c01.y * wx;
            Ox[j] += c01.z * wx - c01.w * wy;  Oy[j] += c01.z * wy + c01.w * wx;
        }
        float nw = wx * cc - wy * ss;
        wy = wx * ss + wy * cc; wx = nw;
    }
    const float sc = 1.f / 128.f;
#pragma unroll
    for (int j = 0; j < 4; ++j) {
        int v = v0 + vg * 4 + j;
        if (v < WF) {
            float WOx = tc * Ox[j] - ts * Oy[j];
            float WOy = tc * Oy[j] + ts * Ox[j];
            gZ[v * 128 + h]      = make_float2((Ex[j] + WOx) * sc, (Ey[j] + WOy) * sc);
            gZ[v * 128 + h + 64] = make_float2((Ex[j] - WOx) * sc, (Ey[j] - WOy) * sc);
        }
    }
}

// ---------------- K6: c2r inverse along v (halfcomplex) + bias ----------------
#define K6P 66
__global__ __launch_bounds__(256) void k_irow(const float2* __restrict__ Zi,
                                              const float* __restrict__ bias,
                                              float* __restrict__ out) {
    __shared__ __align__(16) float2 zi[16 * K6P];
    int t = threadIdx.x;
    int img = blockIdx.x >> 3;
    int h0 = (blockIdx.x & 7) * 16;
    const float2* gZ = Zi + (size_t)img * CPLX_PER_IMG;
    for (int k = t; k < 16 * WF; k += 256) {
        int v = k >> 4, j = k & 15;
        zi[j * K6P + v] = gZ[v * 128 + h0 + j];
    }
    __syncthreads();
    int xh = t & 63, jb = t >> 6;
    float bo = bias[img & 63];
    float s1, c1, s2, c2;
    __sincosf(2.f * PI_F * (float)xh / 128.f, &s1, &c1);
    __sincosf(2.f * PI_F * (float)(2 * xh) / 128.f, &s2, &c2);
    float accP[4], accM[4];
#pragma unroll
    for (int j = 0; j < 4; ++j) { accP[j] = 0.f; accM[j] = 0.f; }
    float wex = 1.f, wey = 0.f;
    float wox = c1, woy = s1;
#pragma unroll 2
    for (int m = 0; m < 32; ++m) {
#pragma unroll
        for (int j = 0; j < 4; ++j) {
            float4 z2 = *(const float4*)&zi[(jb + 4 * j) * K6P + 2 * m];
            accP[j] += z2.x * wex - z2.y * wey;
            accM[j] += z2.z * wox - z2.w * woy;
        }
        float nw = wex * c2 - wey * s2;
        wey = wex * s2 + wey * c2; wex = nw;
        nw = wox * c2 - woy * s2;
        woy = wox * s2 + woy * c2; wox = nw;
    }
    float pm = (xh & 1) ? -1.f : 1.f;
    const float sc = 1.f / 128.f;
    float* gout = out + (size_t)img * 16384;
#pragma unroll
    for (int j = 0; j < 4; ++j) {
        int jr = jb + 4 * j;
        float z0v = zi[jr * K6P + 0].x;
        float z64v = zi[jr * K6P + 64].x;
        float outA = (2.f * (accP[j] + accM[j]) + 2.f * pm * z64v - z0v - pm * z64v) * sc + bo;
        float outB = (2.f * (accP[j] - accM[j]) + 2.f * pm * z64v - z0v - pm * z64v) * sc + bo;
        gout[(h0 + jr) * 128 + xh] = outA;
        gout[(h0 + jr) * 128 + xh + 64] = outB;
    }
}

extern "C" void kernel_launch(void* const* d_in, const int* in_sizes, int n_in,
                              void* d_out, int out_size, void* d_ws, size_t ws_size,
                              hipStream_t stream) {
    const float* x = (const float*)d_in[0];      // [4,64,128,128]
    const float* w = (const float*)d_in[1];      // [64,64,3,3]
    const float* bias = (const float*)d_in[2];   // [64]
    float* out = (float*)d_out;                  // [4,64,128,128]

    float* ws = (float*)d_ws;
    float2* R = (float2*)ws;                                   // 17 MB; reused as Z then Zi
    ushort* XsRe = (ushort*)(ws + R_FLOATS);                   // 4.26 MB bf16 plane
    ushort* XsIm = XsRe + (size_t)NB * NC * CPLX_PER_IMG;      // 4.26 MB
    ushort* WvRe = XsIm + (size_t)NB * NC * CPLX_PER_IMG;      // 1.6 MB
    ushort* WvIm = WvRe + (size_t)3 * WF * NC * NC;            // 1.6 MB

    k_rowfft<<<NB * NC * 4, 256, 0, stream>>>(x, R);
    k_colfft<<<NB * NC * 5, 256, 0, stream>>>(R, XsRe, XsIm);
    k_wv<<<(3 * WF * NC * NC + 255) / 256, 256, 0, stream>>>(w, WvRe, WvIm);
    k_gemm<<<WF * NB, 256, 0, stream>>>(XsRe, XsIm, WvRe, WvIm, R);   // R now holds Z
    k_ifftu<<<NB * NC * 5, 256, 0, stream>>>(R);
    k_irow<<<NB * NC * 8, 256, 0, stream>>>(R, bias, out);
}

// Round 5
// 134.948 us; speedup vs baseline: 6.4163x; 1.1648x over previous
//
#include <hip/hip_runtime.h>

#define PI_F 3.14159265358979323846f

// Problem constants: B=4, Cin=Cout=64, H=W=128, Wf=65, K=3
#define HH 128
#define WW 128
#define WF 65
#define NB 4
#define NC 64
#define CPLX_PER_IMG (HH * WF)                  // 8320

typedef __attribute__((ext_vector_type(8))) short short8;
typedef __attribute__((ext_vector_type(4))) float f32x4;

__device__ __forceinline__ ushort f2b(float f) {   // f32 -> bf16 RNE
    unsigned u = __float_as_uint(f);
    u += 0x7fffu + ((u >> 16) & 1u);
    return (ushort)(u >> 16);
}

// ===================== ws layout (bytes) =====================
// A1: [160][128]  row FFT fwd        @ 0        (40960)
// A2: [256][256]  col FFT fwd        @ 40960    (131072)
// A4: [256][256]  col FFT inv /128   @ 172032   (131072)
// A5: [128][160]  c2r inv /128       @ 303104   (40960)
// WvRe/WvIm: [3][65][64][64]         @ 344064   (2x 1597440)
// Rre/Rim:   [256*65][128]           @ 3538944  (2x 4259840)
// XsRe/XsIm: [256*65][128]           @ 12058624 (2x 4259840)
// Zre/Zim:   [256*65][128]           @ 20578304 (2x 4259840)
// Zire/Ziim: [256*128][80]           @ 29097984 (2x 5242880)   total 39.58 MB

// ---------------- k_mats: build bf16 DFT matrices ----------------
__global__ __launch_bounds__(256) void k_mats(ushort* __restrict__ A1,
                                              ushort* __restrict__ A2,
                                              ushort* __restrict__ A4,
                                              ushort* __restrict__ A5) {
    int idx = blockIdx.x * 256 + threadIdx.x;
    if (idx < 20480) {                       // A1[m][k]: m=part*80+v
        int m = idx >> 7, k = idx & 127;
        int part = m / 80, v = m - part * 80;
        float s, c;
        __sincosf(2.f * PI_F * (float)((v * k) & 127) / 128.f, &s, &c);
        float val = (v < 65) ? (part ? -s : c) : 0.f;
        A1[idx] = f2b(val);
    } else if (idx < 86016) {                // A2[m][k2]: fwd col DFT
        int j = idx - 20480;
        int m = j >> 8, k2 = j & 255;
        int part = m >> 7, u = m & 127;
        int kp = k2 >> 7, h = k2 & 127;
        float s, c;
        __sincosf(2.f * PI_F * (float)((u * h) & 127) / 128.f, &s, &c);
        // C_re = sum cos*Rre + sin*Rim ; C_im = sum -sin*Rre + cos*Rim
        float val = part == 0 ? (kp == 0 ? c : s) : (kp == 0 ? -s : c);
        A2[j] = f2b(val);
    } else if (idx < 151552) {               // A4[m][k2]: inv col DFT, /128
        int j = idx - 86016;
        int m = j >> 8, k2 = j & 255;
        int part = m >> 7, h = m & 127;
        int kp = k2 >> 7, u = k2 & 127;
        float s, c;
        __sincosf(2.f * PI_F * (float)((u * h) & 127) / 128.f, &s, &c);
        // C_re = (cos*Zre - sin*Zim)/128 ; C_im = (sin*Zre + cos*Zim)/128
        float val = part == 0 ? (kp == 0 ? c : -s) : (kp == 0 ? s : c);
        A4[j] = f2b(val * (1.f / 128.f));
    } else {                                 // A5[x][k2]: c2r, /128
        int j = idx - 151552;
        int x = j / 160, k2 = j - x * 160;
        int part = k2 / 80, v = k2 - part * 80;
        float s, c;
        __sincosf(2.f * PI_F * (float)((v * x) & 127) / 128.f, &s, &c);
        float cv = (v == 0 || v == 64) ? 1.f : 2.f;
        float val = (v < 65) ? (part == 0 ? cv * c : -cv * s) * (1.f / 128.f) : 0.f;
        A5[j] = f2b(val);
    }
}

// ---------------- k_zero: zero Zi v-pad [64,80) ----------------
__global__ __launch_bounds__(256) void k_zero(uint* __restrict__ Zire_u,
                                              uint* __restrict__ Ziim_u) {
    int idx = blockIdx.x * 256 + threadIdx.x;     // 2*262144
    uint* p = (idx & 262144) ? Ziim_u : Zire_u;
    int r = (idx & 262143) >> 3, q = idx & 7;
    p[r * 40 + 32 + q] = 0;
}

// ---------------- k_wv: Wv planes [p][v][o][i] bf16 ----------------
__global__ void k_wv(const float* __restrict__ w,
                     ushort* __restrict__ WvRe, ushort* __restrict__ WvIm) {
    int x = blockIdx.x * 256 + threadIdx.x;
    if (x >= 3 * WF * NC * NC) return;
    int i = x & 63;
    int o = (x >> 6) & 63;
    int pv = x >> 12;
    int p = pv / WF;
    int v = pv % WF;
    const float* wp = w + ((size_t)o * 64 + i) * 9 + p * 3;
    float re = wp[0], im = 0.f;
#pragma unroll
    for (int q = 1; q <= 2; ++q) {
        int k = (v * q) & 127;
        float s, c;
        __sincosf(-2.f * PI_F * (float)k / 128.f, &s, &c);
        re += wp[q] * c;
        im += wp[q] * s;
    }
    WvRe[x] = f2b(re);
    WvIm[x] = f2b(im);
}

// ---------------- S1: row rfft via MFMA. C[m=part*80+v][n=img*128+h] ----------------
// block = one img (grid 256); B-tile = x rows in bf16.
#define S1P 136
__global__ __launch_bounds__(256) void k_s1(const float* __restrict__ x,
                                            const ushort* __restrict__ A1,
                                            ushort* __restrict__ Rre,
                                            ushort* __restrict__ Rim) {
    __shared__ ushort B[128 * S1P];          // 34.8 KB
    int t = threadIdx.x;
    int img = blockIdx.x;
    const float* gx = x + (size_t)img * 16384;
    for (int c = t; c < 2048; c += 256) {    // 128 rows x 16 chunks
        int r = c >> 4, sl = c & 15;
        const float* src = gx + r * 128 + sl * 8;
        float4 f0 = *(const float4*)src;
        float4 f1 = *(const float4*)(src + 4);
        short8 v;
        v[0] = (short)f2b(f0.x); v[1] = (short)f2b(f0.y);
        v[2] = (short)f2b(f0.z); v[3] = (short)f2b(f0.w);
        v[4] = (short)f2b(f1.x); v[5] = (short)f2b(f1.y);
        v[6] = (short)f2b(f1.z); v[7] = (short)f2b(f1.w);
        *(short8*)&B[r * S1P + sl * 8] = v;
    }
    __syncthreads();
    int lane = t & 63, wave = t >> 6;
    int lrow = lane & 15, lq = lane >> 4;
    f32x4 acc[10][2];
#pragma unroll
    for (int mt = 0; mt < 10; ++mt)
#pragma unroll
        for (int nt = 0; nt < 2; ++nt) acc[mt][nt] = (f32x4){0.f, 0.f, 0.f, 0.f};
    for (int ks = 0; ks < 4; ++ks) {
        short8 b0 = *(short8*)&B[(wave * 32 + lrow) * S1P + ks * 32 + lq * 8];
        short8 b1 = *(short8*)&B[(wave * 32 + 16 + lrow) * S1P + ks * 32 + lq * 8];
#pragma unroll
        for (int mt = 0; mt < 10; ++mt) {
            short8 a = *(const short8*)&A1[(mt * 16 + lrow) * 128 + ks * 32 + lq * 8];
            acc[mt][0] = __builtin_amdgcn_mfma_f32_16x16x32_bf16(a, b0, acc[mt][0], 0, 0, 0);
            acc[mt][1] = __builtin_amdgcn_mfma_f32_16x16x32_bf16(a, b1, acc[mt][1], 0, 0, 0);
        }
    }
#pragma unroll
    for (int mt = 0; mt < 10; ++mt) {
        int part = mt >= 5;
        ushort* dst = part ? Rim : Rre;
#pragma unroll
        for (int e = 0; e < 4; ++e) {
            int v = mt * 16 + lq * 4 + e - part * 80;
            if (v < 65) {
#pragma unroll
                for (int nt = 0; nt < 2; ++nt) {
                    int h = wave * 32 + nt * 16 + lrow;
                    dst[((size_t)(img * 65 + v)) * 128 + h] = f2b(acc[mt][nt][e]);
                }
            }
        }
    }
}

// ---------------- S2: col fwd DFT + shift + mask. n=(img,v_in), m=(part,u) ----------------
#define S2P 264
__global__ __launch_bounds__(256) void k_s2(const ushort* __restrict__ Rre,
                                            const ushort* __restrict__ Rim,
                                            const ushort* __restrict__ A2,
                                            ushort* __restrict__ XsRe,
                                            ushort* __restrict__ XsIm) {
    __shared__ ushort B[64 * S2P];           // 33.8 KB
    int t = threadIdx.x;
    int n0 = blockIdx.x * 64;
    for (int c = t; c < 2048; c += 256) {    // 64 rows x 32 chunks
        int r = c >> 5, sl = c & 31;
        const ushort* src = (sl < 16 ? Rre : Rim) + (size_t)(n0 + r) * 128 + (sl & 15) * 8;
        *(short8*)&B[r * S2P + sl * 8] = *(const short8*)src;
    }
    __syncthreads();
    int lane = t & 63, wave = t >> 6;
    int lrow = lane & 15, lq = lane >> 4;
    f32x4 acc[16];
#pragma unroll
    for (int mt = 0; mt < 16; ++mt) acc[mt] = (f32x4){0.f, 0.f, 0.f, 0.f};
    for (int ks = 0; ks < 8; ++ks) {
        short8 b = *(short8*)&B[(wave * 16 + lrow) * S2P + ks * 32 + lq * 8];
#pragma unroll
        for (int mt = 0; mt < 16; ++mt) {
            short8 a = *(const short8*)&A2[(mt * 16 + lrow) * 256 + ks * 32 + lq * 8];
            acc[mt] = __builtin_amdgcn_mfma_f32_16x16x32_bf16(a, b, acc[mt], 0, 0, 0);
        }
    }
    int n = n0 + wave * 16 + lrow;
    int img = n / 65, v_in = n - img * 65;
    int v_out = v_in + 32; if (v_out >= 65) v_out -= 65;
    int dv2 = (v_out - 64) * (v_out - 64);
    size_t obase = ((size_t)(img * 65 + v_out)) * 128;
#pragma unroll
    for (int mt = 0; mt < 16; ++mt) {
        int part = mt >> 3;
        ushort* dst = part ? XsIm : XsRe;
#pragma unroll
        for (int e = 0; e < 4; ++e) {
            int u = (mt & 7) * 16 + lq * 4 + e;
            int u_out = (u + 64) & 127;
            int du = u_out - 64;
            bool keep = (du * du + dv2) > 900;
            dst[obase + u_out] = keep ? f2b(acc[mt][e]) : (ushort)0;
        }
    }
}

// ---------------- S3: per-(v,b) complex GEMM via bf16 MFMA + phase fold ----------------
#define AP 72
__global__ __launch_bounds__(256, 2) void k_gemm(const ushort* __restrict__ XsRe,
                                                 const ushort* __restrict__ XsIm,
                                                 const ushort* __restrict__ WvRe,
                                                 const ushort* __restrict__ WvIm,
                                                 ushort* __restrict__ Zre,
                                                 ushort* __restrict__ Zim) {
    __shared__ ushort XTre[128 * AP], XTim[128 * AP];
    __shared__ ushort WSre[64 * AP],  WSim[64 * AP];
    int t = threadIdx.x;
    int v = blockIdx.x >> 2;
    int b = blockIdx.x & 3;

    {
        int u = t & 127, qh = t >> 7;
#pragma unroll
        for (int q8 = 0; q8 < 8; ++q8) {
            int q = qh * 8 + q8;
            ushort re4[4], im4[4];
#pragma unroll
            for (int c = 0; c < 4; ++c) {
                int i = q * 4 + c;
                size_t off = ((size_t)(b * 64 + i) * WF + v) * 128 + u;
                re4[c] = XsRe[off];
                im4[c] = XsIm[off];
            }
            *(ushort4*)&XTre[u * AP + q * 4] = make_ushort4(re4[0], re4[1], re4[2], re4[3]);
            *(ushort4*)&XTim[u * AP + q * 4] = make_ushort4(im4[0], im4[1], im4[2], im4[3]);
        }
    }

    int lane = t & 63, wave = t >> 6;
    int lrow = lane & 15, lq = lane >> 4;
    int u0 = wave * 32;

    f32x4 fRe[8], fIm[8];
#pragma unroll
    for (int m = 0; m < 8; ++m) {
        fRe[m] = (f32x4){0.f, 0.f, 0.f, 0.f};
        fIm[m] = (f32x4){0.f, 0.f, 0.f, 0.f};
    }

    for (int p = 0; p < 3; ++p) {
        if (p) __syncthreads();
        {
            const ushort* gr = WvRe + ((size_t)(p * WF + v)) * 4096;
            const ushort* gi = WvIm + ((size_t)(p * WF + v)) * 4096;
#pragma unroll
            for (int cc = 0; cc < 2; ++cc) {
                int c = t + cc * 256;
                int o = c >> 3, i0 = (c & 7) * 8;
                *(short8*)&WSre[o * AP + i0] = *(const short8*)&gr[c * 8];
                *(short8*)&WSim[o * AP + i0] = *(const short8*)&gi[c * 8];
            }
        }
        __syncthreads();

        f32x4 pRe[8], pIm[8];
#pragma unroll
        for (int m = 0; m < 8; ++m) {
            pRe[m] = (f32x4){0.f, 0.f, 0.f, 0.f};
            pIm[m] = (f32x4){0.f, 0.f, 0.f, 0.f};
        }
#pragma unroll
        for (int ks = 0; ks < 2; ++ks) {
            int kb = ks * 32 + lq * 8;
            short8 br[2], bi[2], bin[2];
#pragma unroll
            for (int ut = 0; ut < 2; ++ut) {
                int u = u0 + ut * 16 + lrow;
                br[ut] = *(const short8*)&XTre[u * AP + kb];
                bi[ut] = *(const short8*)&XTim[u * AP + kb];
                bin[ut] = bi[ut] ^ (short)0x8000;
            }
#pragma unroll
            for (int ot = 0; ot < 4; ++ot) {
                int o = ot * 16 + lrow;
                short8 ar = *(const short8*)&WSre[o * AP + kb];
                short8 ai = *(const short8*)&WSim[o * AP + kb];
#pragma unroll
                for (int ut = 0; ut < 2; ++ut) {
                    int m = ot * 2 + ut;
                    pRe[m] = __builtin_amdgcn_mfma_f32_16x16x32_bf16(ai, bin[ut], pRe[m], 0, 0, 0);
                    pRe[m] = __builtin_amdgcn_mfma_f32_16x16x32_bf16(ar, br[ut],  pRe[m], 0, 0, 0);
                    pIm[m] = __builtin_amdgcn_mfma_f32_16x16x32_bf16(ai, br[ut],  pIm[m], 0, 0, 0);
                    pIm[m] = __builtin_amdgcn_mfma_f32_16x16x32_bf16(ar, bi[ut],  pIm[m], 0, 0, 0);
                }
            }
        }
#pragma unroll
        for (int ut = 0; ut < 2; ++ut) {
            int u = u0 + ut * 16 + lrow;
            float sn, cn;
            __sincosf(-2.f * PI_F * (float)(u * p) / 128.f, &sn, &cn);
#pragma unroll
            for (int ot = 0; ot < 4; ++ot) {
                int m = ot * 2 + ut;
#pragma unroll
                for (int e = 0; e < 4; ++e) {
                    fRe[m][e] += pRe[m][e] * cn - pIm[m][e] * sn;
                    fIm[m][e] += pIm[m][e] * cn + pRe[m][e] * sn;
                }
            }
        }
    }

#pragma unroll
    for (int ot = 0; ot < 4; ++ot)
#pragma unroll
        for (int ut = 0; ut < 2; ++ut) {
            int m = ot * 2 + ut;
            int u = u0 + ut * 16 + lrow;
#pragma unroll
            for (int e = 0; e < 4; ++e) {
                int o = ot * 16 + lq * 4 + e;
                size_t idx = ((size_t)(b * 64 + o) * 65 + v) * 128 + u;
                Zre[idx] = f2b(fRe[m][e]);
                Zim[idx] = f2b(fIm[m][e]);
            }
        }
}

// ---------------- S4: col inverse DFT (/128). n=(ch,v), m=(part,h) ----------------
__global__ __launch_bounds__(256) void k_s4(const ushort* __restrict__ Zre,
                                            const ushort* __restrict__ Zim,
                                            const ushort* __restrict__ A4,
                                            ushort* __restrict__ Zire,
                                            ushort* __restrict__ Ziim) {
    __shared__ ushort B[64 * S2P];
    int t = threadIdx.x;
    int n0 = blockIdx.x * 64;
    for (int c = t; c < 2048; c += 256) {
        int r = c >> 5, sl = c & 31;
        const ushort* src = (sl < 16 ? Zre : Zim) + (size_t)(n0 + r) * 128 + (sl & 15) * 8;
        *(short8*)&B[r * S2P + sl * 8] = *(const short8*)src;
    }
    __syncthreads();
    int lane = t & 63, wave = t >> 6;
    int lrow = lane & 15, lq = lane >> 4;
    f32x4 acc[16];
#pragma unroll
    for (int mt = 0; mt < 16; ++mt) acc[mt] = (f32x4){0.f, 0.f, 0.f, 0.f};
    for (int ks = 0; ks < 8; ++ks) {
        short8 b = *(short8*)&B[(wave * 16 + lrow) * S2P + ks * 32 + lq * 8];
#pragma unroll
        for (int mt = 0; mt < 16; ++mt) {
            short8 a = *(const short8*)&A4[(mt * 16 + lrow) * 256 + ks * 32 + lq * 8];
            acc[mt] = __builtin_amdgcn_mfma_f32_16x16x32_bf16(a, b, acc[mt], 0, 0, 0);
        }
    }
    int n = n0 + wave * 16 + lrow;
    int ch = n / 65, v = n - ch * 65;
#pragma unroll
    for (int mt = 0; mt < 16; ++mt) {
        int part = mt >> 3;
        ushort* dst = part ? Ziim : Zire;
#pragma unroll
        for (int e = 0; e < 4; ++e) {
            int h = (mt & 7) * 16 + lq * 4 + e;
            dst[((size_t)(ch * 128 + h)) * 80 + v] = f2b(acc[mt][e]);
        }
    }
}

// ---------------- S5: c2r inverse along v + bias. n=(ch,h), m=x ----------------
#define S5P 168
__global__ __launch_bounds__(256) void k_s5(const ushort* __restrict__ Zire,
                                            const ushort* __restrict__ Ziim,
                                            const ushort* __restrict__ A5,
                                            const float* __restrict__ bias,
                                            float* __restrict__ out) {
    __shared__ ushort B[128 * S5P];          // 43 KB
    int t = threadIdx.x;
    int ch = blockIdx.x;                     // n0 = ch*128
    for (int c = t; c < 2560; c += 256) {    // 128 rows x 20 chunks
        int r = c / 20, sl = c - r * 20;
        const ushort* src = (sl < 10 ? Zire : Ziim) + ((size_t)(ch * 128 + r)) * 80
                            + (sl < 10 ? sl : sl - 10) * 8;
        *(short8*)&B[r * S5P + sl * 8] = *(const short8*)src;
    }
    __syncthreads();
    int lane = t & 63, wave = t >> 6;
    int lrow = lane & 15, lq = lane >> 4;
    f32x4 acc[8][2];
#pragma unroll
    for (int mt = 0; mt < 8; ++mt)
#pragma unroll
        for (int nt = 0; nt < 2; ++nt) acc[mt][nt] = (f32x4){0.f, 0.f, 0.f, 0.f};
    for (int ks = 0; ks < 5; ++ks) {
        short8 b0 = *(short8*)&B[(wave * 32 + lrow) * S5P + ks * 32 + lq * 8];
        short8 b1 = *(short8*)&B[(wave * 32 + 16 + lrow) * S5P + ks * 32 + lq * 8];
#pragma unroll
        for (int mt = 0; mt < 8; ++mt) {
            short8 a = *(const short8*)&A5[(mt * 16 + lrow) * 160 + ks * 32 + lq * 8];
            acc[mt][0] = __builtin_amdgcn_mfma_f32_16x16x32_bf16(a, b0, acc[mt][0], 0, 0, 0);
            acc[mt][1] = __builtin_amdgcn_mfma_f32_16x16x32_bf16(a, b1, acc[mt][1], 0, 0, 0);
        }
    }
    float bo = bias[ch & 63];
    float* go = out + (size_t)ch * 16384;
#pragma unroll
    for (int mt = 0; mt < 8; ++mt) {
        int x0 = mt * 16 + lq * 4;
#pragma unroll
        for (int nt = 0; nt < 2; ++nt) {
            int h = wave * 32 + nt * 16 + lrow;
            float4 r4;
            r4.x = acc[mt][nt][0] + bo;
            r4.y = acc[mt][nt][1] + bo;
            r4.z = acc[mt][nt][2] + bo;
            r4.w = acc[mt][nt][3] + bo;
            *(float4*)&go[h * 128 + x0] = r4;
        }
    }
}

extern "C" void kernel_launch(void* const* d_in, const int* in_sizes, int n_in,
                              void* d_out, int out_size, void* d_ws, size_t ws_size,
                              hipStream_t stream) {
    const float* x = (const float*)d_in[0];      // [4,64,128,128]
    const float* w = (const float*)d_in[1];      // [64,64,3,3]
    const float* bias = (const float*)d_in[2];   // [64]
    float* out = (float*)d_out;                  // [4,64,128,128]

    char* ws = (char*)d_ws;
    ushort* A1   = (ushort*)(ws + 0);
    ushort* A2   = (ushort*)(ws + 40960);
    ushort* A4   = (ushort*)(ws + 172032);
    ushort* A5   = (ushort*)(ws + 303104);
    ushort* WvRe = (ushort*)(ws + 344064);
    ushort* WvIm = (ushort*)(ws + 1941504);
    ushort* Rre  = (ushort*)(ws + 3538944);
    ushort* Rim  = (ushort*)(ws + 7798784);
    ushort* XsRe = (ushort*)(ws + 12058624);
    ushort* XsIm = (ushort*)(ws + 16318464);
    ushort* Zre  = (ushort*)(ws + 20578304);
    ushort* Zim  = (ushort*)(ws + 24838144);
    ushort* Zire = (ushort*)(ws + 29097984);
    ushort* Ziim = (ushort*)(ws + 34340864);

    k_mats<<<672, 256, 0, stream>>>(A1, A2, A4, A5);
    k_zero<<<2048, 256, 0, stream>>>((uint*)Zire, (uint*)Ziim);
    k_wv<<<(3 * WF * NC * NC + 255) / 256, 256, 0, stream>>>(w, WvRe, WvIm);
    k_s1<<<256, 256, 0, stream>>>(x, A1, Rre, Rim);
    k_s2<<<260, 256, 0, stream>>>(Rre, Rim, A2, XsRe, XsIm);
    k_gemm<<<WF * NB, 256, 0, stream>>>(XsRe, XsIm, WvRe, WvIm, Zre, Zim);
    k_s4<<<260, 256, 0, stream>>>(Zre, Zim, A4, Zire, Ziim);
    k_s5<<<256, 256, 0, stream>>>(Zire, Ziim, A5, bias, out);
}

// Round 6
// 124.307 us; speedup vs baseline: 6.9655x; 1.0856x over previous
//
#include <hip/hip_runtime.h>

#define PI_F 3.14159265358979323846f

// Problem constants: B=4, Cin=Cout=64, H=W=128, Wf=65, K=3
#define HH 128
#define WW 128
#define WF 65
#define NB 4
#define NC 64
#define CPLX_PER_IMG (HH * WF)                  // 8320

typedef __attribute__((ext_vector_type(8))) short short8;
typedef __attribute__((ext_vector_type(4))) float f32x4;

__device__ __forceinline__ ushort f2b(float f) {   // f32 -> bf16 RNE
    unsigned u = __float_as_uint(f);
    u += 0x7fffu + ((u >> 16) & 1u);
    return (ushort)(u >> 16);
}

// ===================== ws layout (bytes) =====================
// A1: [160][128]  row FFT fwd        @ 0        (40960)
// A2: [256][256]  col FFT fwd        @ 40960    (131072)
// A4: [256][256]  col FFT inv /128   @ 172032   (131072)
// A5: [128][160]  c2r inv /128       @ 303104   (40960)
// WvRe/WvIm: [3][65][64][64]         @ 344064   (2x 1597440)
// Rre/Rim:   [256*65][128]           @ 3538944  (2x 4259840)
// XsRe/XsIm: [256*65][128]           @ 12058624 (2x 4259840)
// Zre/Zim:   [256*65][128]           @ 20578304 (2x 4259840)
// Zire/Ziim: [256*128][80]           @ 29097984 (2x 5242880)   total 39.58 MB

// ---------------- k_mats: build bf16 DFT matrices ----------------
__global__ __launch_bounds__(256) void k_mats(ushort* __restrict__ A1,
                                              ushort* __restrict__ A2,
                                              ushort* __restrict__ A4,
                                              ushort* __restrict__ A5) {
    int idx = blockIdx.x * 256 + threadIdx.x;
    if (idx < 20480) {                       // A1[m][k]: m=part*80+v
        int m = idx >> 7, k = idx & 127;
        int part = m / 80, v = m - part * 80;
        float s, c;
        __sincosf(2.f * PI_F * (float)((v * k) & 127) / 128.f, &s, &c);
        float val = (v < 65) ? (part ? -s : c) : 0.f;
        A1[idx] = f2b(val);
    } else if (idx < 86016) {                // A2[m][k2]: fwd col DFT
        int j = idx - 20480;
        int m = j >> 8, k2 = j & 255;
        int part = m >> 7, u = m & 127;
        int kp = k2 >> 7, h = k2 & 127;
        float s, c;
        __sincosf(2.f * PI_F * (float)((u * h) & 127) / 128.f, &s, &c);
        float val = part == 0 ? (kp == 0 ? c : s) : (kp == 0 ? -s : c);
        A2[j] = f2b(val);
    } else if (idx < 151552) {               // A4[m][k2]: inv col DFT, /128
        int j = idx - 86016;
        int m = j >> 8, k2 = j & 255;
        int part = m >> 7, h = m & 127;
        int kp = k2 >> 7, u = k2 & 127;
        float s, c;
        __sincosf(2.f * PI_F * (float)((u * h) & 127) / 128.f, &s, &c);
        float val = part == 0 ? (kp == 0 ? c : -s) : (kp == 0 ? s : c);
        A4[j] = f2b(val * (1.f / 128.f));
    } else {                                 // A5[x][k2]: c2r, /128
        int j = idx - 151552;
        int x = j / 160, k2 = j - x * 160;
        int part = k2 / 80, v = k2 - part * 80;
        float s, c;
        __sincosf(2.f * PI_F * (float)((v * x) & 127) / 128.f, &s, &c);
        float cv = (v == 0 || v == 64) ? 1.f : 2.f;
        float val = (v < 65) ? (part == 0 ? cv * c : -cv * s) * (1.f / 128.f) : 0.f;
        A5[j] = f2b(val);
    }
}

// ---------------- k_zero: zero Zi v-pad [64,80) ----------------
__global__ __launch_bounds__(256) void k_zero(uint* __restrict__ Zire_u,
                                              uint* __restrict__ Ziim_u) {
    int idx = blockIdx.x * 256 + threadIdx.x;     // 2*262144
    uint* p = (idx & 262144) ? Ziim_u : Zire_u;
    int r = (idx & 262143) >> 3, q = idx & 7;
    p[r * 40 + 32 + q] = 0;
}

// ---------------- k_wv: Wv planes [p][v][o][i] bf16 ----------------
__global__ void k_wv(const float* __restrict__ w,
                     ushort* __restrict__ WvRe, ushort* __restrict__ WvIm) {
    int x = blockIdx.x * 256 + threadIdx.x;
    if (x >= 3 * WF * NC * NC) return;
    int i = x & 63;
    int o = (x >> 6) & 63;
    int pv = x >> 12;
    int p = pv / WF;
    int v = pv % WF;
    const float* wp = w + ((size_t)o * 64 + i) * 9 + p * 3;
    float re = wp[0], im = 0.f;
#pragma unroll
    for (int q = 1; q <= 2; ++q) {
        int k = (v * q) & 127;
        float s, c;
        __sincosf(-2.f * PI_F * (float)k / 128.f, &s, &c);
        re += wp[q] * c;
        im += wp[q] * s;
    }
    WvRe[x] = f2b(re);
    WvIm[x] = f2b(im);
}

// ---------------- S1: row rfft via MFMA. C[m=part*80+v][n=img*128+h] ----------------
#define S1P 136
__global__ __launch_bounds__(256) void k_s1(const float* __restrict__ x,
                                            const ushort* __restrict__ A1,
                                            ushort* __restrict__ Rre,
                                            ushort* __restrict__ Rim) {
    __shared__ ushort B[128 * S1P];          // 34.8 KB
    int t = threadIdx.x;
    int img = blockIdx.x;
    const float* gx = x + (size_t)img * 16384;
    for (int c = t; c < 2048; c += 256) {    // 128 rows x 16 chunks
        int r = c >> 4, sl = c & 15;
        const float* src = gx + r * 128 + sl * 8;
        float4 f0 = *(const float4*)src;
        float4 f1 = *(const float4*)(src + 4);
        short8 v;
        v[0] = (short)f2b(f0.x); v[1] = (short)f2b(f0.y);
        v[2] = (short)f2b(f0.z); v[3] = (short)f2b(f0.w);
        v[4] = (short)f2b(f1.x); v[5] = (short)f2b(f1.y);
        v[6] = (short)f2b(f1.z); v[7] = (short)f2b(f1.w);
        *(short8*)&B[r * S1P + sl * 8] = v;
    }
    __syncthreads();
    int lane = t & 63, wave = t >> 6;
    int lrow = lane & 15, lq = lane >> 4;
    f32x4 acc[10][2];
#pragma unroll
    for (int mt = 0; mt < 10; ++mt)
#pragma unroll
        for (int nt = 0; nt < 2; ++nt) acc[mt][nt] = (f32x4){0.f, 0.f, 0.f, 0.f};
    for (int ks = 0; ks < 4; ++ks) {
        short8 b0 = *(short8*)&B[(wave * 32 + lrow) * S1P + ks * 32 + lq * 8];
        short8 b1 = *(short8*)&B[(wave * 32 + 16 + lrow) * S1P + ks * 32 + lq * 8];
#pragma unroll
        for (int mt = 0; mt < 10; ++mt) {
            short8 a = *(const short8*)&A1[(mt * 16 + lrow) * 128 + ks * 32 + lq * 8];
            acc[mt][0] = __builtin_amdgcn_mfma_f32_16x16x32_bf16(a, b0, acc[mt][0], 0, 0, 0);
            acc[mt][1] = __builtin_amdgcn_mfma_f32_16x16x32_bf16(a, b1, acc[mt][1], 0, 0, 0);
        }
    }
#pragma unroll
    for (int mt = 0; mt < 10; ++mt) {
        int part = mt >= 5;
        ushort* dst = part ? Rim : Rre;
#pragma unroll
        for (int e = 0; e < 4; ++e) {
            int v = mt * 16 + lq * 4 + e - part * 80;
            if (v < 65) {
#pragma unroll
                for (int nt = 0; nt < 2; ++nt) {
                    int h = wave * 32 + nt * 16 + lrow;
                    dst[((size_t)(img * 65 + v)) * 128 + h] = f2b(acc[mt][nt][e]);
                }
            }
        }
    }
}

// ---------------- S2: col fwd DFT + shift + mask. n=(img,v_in), m=(part,u) ----------------
// Epilogue: masked bf16 -> LDS C-tile [2][64][132] (reusing B), then coalesced copy-out.
#define S2P 264
#define CP 132
__global__ __launch_bounds__(256) void k_s2(const ushort* __restrict__ Rre,
                                            const ushort* __restrict__ Rim,
                                            const ushort* __restrict__ A2,
                                            ushort* __restrict__ XsRe,
                                            ushort* __restrict__ XsIm) {
    __shared__ ushort B[64 * S2P];           // 33792 B; reused as C[2][64][132]
    int t = threadIdx.x;
    int n0 = blockIdx.x * 64;
    for (int c = t; c < 2048; c += 256) {    // 64 rows x 32 chunks
        int r = c >> 5, sl = c & 31;
        const ushort* src = (sl < 16 ? Rre : Rim) + (size_t)(n0 + r) * 128 + (sl & 15) * 8;
        *(short8*)&B[r * S2P + sl * 8] = *(const short8*)src;
    }
    __syncthreads();
    int lane = t & 63, wave = t >> 6;
    int lrow = lane & 15, lq = lane >> 4;
    f32x4 acc[16];
#pragma unroll
    for (int mt = 0; mt < 16; ++mt) acc[mt] = (f32x4){0.f, 0.f, 0.f, 0.f};
    for (int ks = 0; ks < 8; ++ks) {
        short8 b = *(short8*)&B[(wave * 16 + lrow) * S2P + ks * 32 + lq * 8];
#pragma unroll
        for (int mt = 0; mt < 16; ++mt) {
            short8 a = *(const short8*)&A2[(mt * 16 + lrow) * 256 + ks * 32 + lq * 8];
            acc[mt] = __builtin_amdgcn_mfma_f32_16x16x32_bf16(a, b, acc[mt], 0, 0, 0);
        }
    }
    // ---- epilogue: mask+shift into LDS C-tile, then coalesced stores ----
    int nl = wave * 16 + lrow;               // local row 0..63 (this lane's n)
    int n = n0 + nl;
    int img = n / 65, v_in = n - img * 65;
    int v_out = v_in + 32; if (v_out >= 65) v_out -= 65;
    int dv2 = (v_out - 64) * (v_out - 64);
    __syncthreads();                         // all B reads done before reuse
#pragma unroll
    for (int mt = 0; mt < 16; ++mt) {
        int part = mt >> 3;
        int ub = (((mt & 7) * 16 + lq * 4) + 64) & 127;   // u_out base, 4 consecutive
        ushort4 pk;
        {
            int du = ub + 0 - 64; pk.x = (du * du + dv2) > 900 ? f2b(acc[mt][0]) : (ushort)0;
            du = ub + 1 - 64;     pk.y = (du * du + dv2) > 900 ? f2b(acc[mt][1]) : (ushort)0;
            du = ub + 2 - 64;     pk.z = (du * du + dv2) > 900 ? f2b(acc[mt][2]) : (ushort)0;
            du = ub + 3 - 64;     pk.w = (du * du + dv2) > 900 ? f2b(acc[mt][3]) : (ushort)0;
        }
        *(ushort4*)&B[(part * 64 + nl) * CP + ub] = pk;
    }
    __syncthreads();
    for (int c = t; c < 2048; c += 256) {    // 2 planes x 64 rows x 16 chunks
        int row = c >> 4, sl = c & 15;       // row = part*64 + nl
        int nlr = row & 63;
        int nr = n0 + nlr;
        int imr = nr / 65, vr = nr - imr * 65;
        int vo = vr + 32; if (vo >= 65) vo -= 65;
        ushort* dst = (row < 64) ? XsRe : XsIm;
        *(short8*)&dst[((size_t)(imr * 65 + vo)) * 128 + sl * 8] =
            *(const short8*)&B[row * CP + sl * 8];
    }
}

// ---------------- S3: per-(v,b) complex GEMM via bf16 MFMA + phase fold ----------------
#define AP 72
__global__ __launch_bounds__(256, 2) void k_gemm(const ushort* __restrict__ XsRe,
                                                 const ushort* __restrict__ XsIm,
                                                 const ushort* __restrict__ WvRe,
                                                 const ushort* __restrict__ WvIm,
                                                 ushort* __restrict__ Zre,
                                                 ushort* __restrict__ Zim) {
    __shared__ ushort XTre[128 * AP], XTim[128 * AP];
    __shared__ ushort WSre[64 * AP],  WSim[64 * AP];
    int t = threadIdx.x;
    int v = blockIdx.x >> 2;
    int b = blockIdx.x & 3;

    {
        int u = t & 127, qh = t >> 7;
#pragma unroll
        for (int q8 = 0; q8 < 8; ++q8) {
            int q = qh * 8 + q8;
            ushort re4[4], im4[4];
#pragma unroll
            for (int c = 0; c < 4; ++c) {
                int i = q * 4 + c;
                size_t off = ((size_t)(b * 64 + i) * WF + v) * 128 + u;
                re4[c] = XsRe[off];
                im4[c] = XsIm[off];
            }
            *(ushort4*)&XTre[u * AP + q * 4] = make_ushort4(re4[0], re4[1], re4[2], re4[3]);
            *(ushort4*)&XTim[u * AP + q * 4] = make_ushort4(im4[0], im4[1], im4[2], im4[3]);
        }
    }

    int lane = t & 63, wave = t >> 6;
    int lrow = lane & 15, lq = lane >> 4;
    int u0 = wave * 32;

    f32x4 fRe[8], fIm[8];
#pragma unroll
    for (int m = 0; m < 8; ++m) {
        fRe[m] = (f32x4){0.f, 0.f, 0.f, 0.f};
        fIm[m] = (f32x4){0.f, 0.f, 0.f, 0.f};
    }

    for (int p = 0; p < 3; ++p) {
        if (p) __syncthreads();
        {
            const ushort* gr = WvRe + ((size_t)(p * WF + v)) * 4096;
            const ushort* gi = WvIm + ((size_t)(p * WF + v)) * 4096;
#pragma unroll
            for (int cc = 0; cc < 2; ++cc) {
                int c = t + cc * 256;
                int o = c >> 3, i0 = (c & 7) * 8;
                *(short8*)&WSre[o * AP + i0] = *(const short8*)&gr[c * 8];
                *(short8*)&WSim[o * AP + i0] = *(const short8*)&gi[c * 8];
            }
        }
        __syncthreads();

        f32x4 pRe[8], pIm[8];
#pragma unroll
        for (int m = 0; m < 8; ++m) {
            pRe[m] = (f32x4){0.f, 0.f, 0.f, 0.f};
            pIm[m] = (f32x4){0.f, 0.f, 0.f, 0.f};
        }
#pragma unroll
        for (int ks = 0; ks < 2; ++ks) {
            int kb = ks * 32 + lq * 8;
            short8 br[2], bi[2], bin[2];
#pragma unroll
            for (int ut = 0; ut < 2; ++ut) {
                int u = u0 + ut * 16 + lrow;
                br[ut] = *(const short8*)&XTre[u * AP + kb];
                bi[ut] = *(const short8*)&XTim[u * AP + kb];
                bin[ut] = bi[ut] ^ (short)0x8000;
            }
#pragma unroll
            for (int ot = 0; ot < 4; ++ot) {
                int o = ot * 16 + lrow;
                short8 ar = *(const short8*)&WSre[o * AP + kb];
                short8 ai = *(const short8*)&WSim[o * AP + kb];
#pragma unroll
                for (int ut = 0; ut < 2; ++ut) {
                    int m = ot * 2 + ut;
                    pRe[m] = __builtin_amdgcn_mfma_f32_16x16x32_bf16(ai, bin[ut], pRe[m], 0, 0, 0);
                    pRe[m] = __builtin_amdgcn_mfma_f32_16x16x32_bf16(ar, br[ut],  pRe[m], 0, 0, 0);
                    pIm[m] = __builtin_amdgcn_mfma_f32_16x16x32_bf16(ai, br[ut],  pIm[m], 0, 0, 0);
                    pIm[m] = __builtin_amdgcn_mfma_f32_16x16x32_bf16(ar, bi[ut],  pIm[m], 0, 0, 0);
                }
            }
        }
#pragma unroll
        for (int ut = 0; ut < 2; ++ut) {
            int u = u0 + ut * 16 + lrow;
            float sn, cn;
            __sincosf(-2.f * PI_F * (float)(u * p) / 128.f, &sn, &cn);
#pragma unroll
            for (int ot = 0; ot < 4; ++ot) {
                int m = ot * 2 + ut;
#pragma unroll
                for (int e = 0; e < 4; ++e) {
                    fRe[m][e] += pRe[m][e] * cn - pIm[m][e] * sn;
                    fIm[m][e] += pIm[m][e] * cn + pRe[m][e] * sn;
                }
            }
        }
    }

#pragma unroll
    for (int ot = 0; ot < 4; ++ot)
#pragma unroll
        for (int ut = 0; ut < 2; ++ut) {
            int m = ot * 2 + ut;
            int u = u0 + ut * 16 + lrow;
#pragma unroll
            for (int e = 0; e < 4; ++e) {
                int o = ot * 16 + lq * 4 + e;
                size_t idx = ((size_t)(b * 64 + o) * 65 + v) * 128 + u;
                Zre[idx] = f2b(fRe[m][e]);
                Zim[idx] = f2b(fIm[m][e]);
            }
        }
}

// ---------------- S4: col inverse DFT (/128). n=(ch,v), m=(part,h) ----------------
__global__ __launch_bounds__(256) void k_s4(const ushort* __restrict__ Zre,
                                            const ushort* __restrict__ Zim,
                                            const ushort* __restrict__ A4,
                                            ushort* __restrict__ Zire,
                                            ushort* __restrict__ Ziim) {
    __shared__ ushort B[64 * S2P];
    int t = threadIdx.x;
    int n0 = blockIdx.x * 64;
    for (int c = t; c < 2048; c += 256) {
        int r = c >> 5, sl = c & 31;
        const ushort* src = (sl < 16 ? Zre : Zim) + (size_t)(n0 + r) * 128 + (sl & 15) * 8;
        *(short8*)&B[r * S2P + sl * 8] = *(const short8*)src;
    }
    __syncthreads();
    int lane = t & 63, wave = t >> 6;
    int lrow = lane & 15, lq = lane >> 4;
    f32x4 acc[16];
#pragma unroll
    for (int mt = 0; mt < 16; ++mt) acc[mt] = (f32x4){0.f, 0.f, 0.f, 0.f};
    for (int ks = 0; ks < 8; ++ks) {
        short8 b = *(short8*)&B[(wave * 16 + lrow) * S2P + ks * 32 + lq * 8];
#pragma unroll
        for (int mt = 0; mt < 16; ++mt) {
            short8 a = *(const short8*)&A4[(mt * 16 + lrow) * 256 + ks * 32 + lq * 8];
            acc[mt] = __builtin_amdgcn_mfma_f32_16x16x32_bf16(a, b, acc[mt], 0, 0, 0);
        }
    }
    int n = n0 + wave * 16 + lrow;
    int ch = n / 65, v = n - ch * 65;
#pragma unroll
    for (int mt = 0; mt < 16; ++mt) {
        int part = mt >> 3;
        ushort* dst = part ? Ziim : Zire;
#pragma unroll
        for (int e = 0; e < 4; ++e) {
            int h = (mt & 7) * 16 + lq * 4 + e;
            dst[((size_t)(ch * 128 + h)) * 80 + v] = f2b(acc[mt][e]);
        }
    }
}

// ---------------- S5: c2r inverse along v + bias. n=(ch,h), m=x ----------------
#define S5P 168
__global__ __launch_bounds__(256) void k_s5(const ushort* __restrict__ Zire,
                                            const ushort* __restrict__ Ziim,
                                            const ushort* __restrict__ A5,
                                            const float* __restrict__ bias,
                                            float* __restrict__ out) {
    __shared__ ushort B[128 * S5P];          // 43 KB
    int t = threadIdx.x;
    int ch = blockIdx.x;                     // n0 = ch*128
    for (int c = t; c < 2560; c += 256) {    // 128 rows x 20 chunks
        int r = c / 20, sl = c - r * 20;
        const ushort* src = (sl < 10 ? Zire : Ziim) + ((size_t)(ch * 128 + r)) * 80
                            + (sl < 10 ? sl : sl - 10) * 8;
        *(short8*)&B[r * S5P + sl * 8] = *(const short8*)src;
    }
    __syncthreads();
    int lane = t & 63, wave = t >> 6;
    int lrow = lane & 15, lq = lane >> 4;
    f32x4 acc[8][2];
#pragma unroll
    for (int mt = 0; mt < 8; ++mt)
#pragma unroll
        for (int nt = 0; nt < 2; ++nt) acc[mt][nt] = (f32x4){0.f, 0.f, 0.f, 0.f};
    for (int ks = 0; ks < 5; ++ks) {
        short8 b0 = *(short8*)&B[(wave * 32 + lrow) * S5P + ks * 32 + lq * 8];
        short8 b1 = *(short8*)&B[(wave * 32 + 16 + lrow) * S5P + ks * 32 + lq * 8];
#pragma unroll
        for (int mt = 0; mt < 8; ++mt) {
            short8 a = *(const short8*)&A5[(mt * 16 + lrow) * 160 + ks * 32 + lq * 8];
            acc[mt][0] = __builtin_amdgcn_mfma_f32_16x16x32_bf16(a, b0, acc[mt][0], 0, 0, 0);
            acc[mt][1] = __builtin_amdgcn_mfma_f32_16x16x32_bf16(a, b1, acc[mt][1], 0, 0, 0);
        }
    }
    float bo = bias[ch & 63];
    float* go = out + (size_t)ch * 16384;
#pragma unroll
    for (int mt = 0; mt < 8; ++mt) {
        int x0 = mt * 16 + lq * 4;
#pragma unroll
        for (int nt = 0; nt < 2; ++nt) {
            int h = wave * 32 + nt * 16 + lrow;
            float4 r4;
            r4.x = acc[mt][nt][0] + bo;
            r4.y = acc[mt][nt][1] + bo;
            r4.z = acc[mt][nt][2] + bo;
            r4.w = acc[mt][nt][3] + bo;
            *(float4*)&go[h * 128 + x0] = r4;
        }
    }
}

extern "C" void kernel_launch(void* const* d_in, const int* in_sizes, int n_in,
                              void* d_out, int out_size, void* d_ws, size_t ws_size,
                              hipStream_t stream) {
    const float* x = (const float*)d_in[0];      // [4,64,128,128]
    const float* w = (const float*)d_in[1];      // [64,64,3,3]
    const float* bias = (const float*)d_in[2];   // [64]
    float* out = (float*)d_out;                  // [4,64,128,128]

    char* ws = (char*)d_ws;
    ushort* A1   = (ushort*)(ws + 0);
    ushort* A2   = (ushort*)(ws + 40960);
    ushort* A4   = (ushort*)(ws + 172032);
    ushort* A5   = (ushort*)(ws + 303104);
    ushort* WvRe = (ushort*)(ws + 344064);
    ushort* WvIm = (ushort*)(ws + 1941504);
    ushort* Rre  = (ushort*)(ws + 3538944);
    ushort* Rim  = (ushort*)(ws + 7798784);
    ushort* XsRe = (ushort*)(ws + 12058624);
    ushort* XsIm = (ushort*)(ws + 16318464);
    ushort* Zre  = (ushort*)(ws + 20578304);
    ushort* Zim  = (ushort*)(ws + 24838144);
    ushort* Zire = (ushort*)(ws + 29097984);
    ushort* Ziim = (ushort*)(ws + 34340864);

    k_mats<<<672, 256, 0, stream>>>(A1, A2, A4, A5);
    k_zero<<<2048, 256, 0, stream>>>((uint*)Zire, (uint*)Ziim);
    k_wv<<<(3 * WF * NC * NC + 255) / 256, 256, 0, stream>>>(w, WvRe, WvIm);
    k_s1<<<256, 256, 0, stream>>>(x, A1, Rre, Rim);
    k_s2<<<260, 256, 0, stream>>>(Rre, Rim, A2, XsRe, XsIm);
    k_gemm<<<WF * NB, 256, 0, stream>>>(XsRe, XsIm, WvRe, WvIm, Zre, Zim);
    k_s4<<<260, 256, 0, stream>>>(Zre, Zim, A4, Zire, Ziim);
    k_s5<<<256, 256, 0, stream>>>(Zire, Ziim, A5, bias, out);
}

// Round 7
// 55.138 us; speedup vs baseline: 15.7037x; 2.2545x over previous
//
#include <hip/hip_runtime.h>

#define PI_F 3.14159265358979323846f

// Problem constants: B=4, Cin=Cout=64, H=W=128, Wf=65, K=3
#define HH 128
#define WW 128
#define WF 65
#define NB 4
#define NC 64
#define CPLX_PER_IMG (HH * WF)                  // 8320

typedef __attribute__((ext_vector_type(8))) short short8;
typedef __attribute__((ext_vector_type(4))) float f32x4;

__device__ __forceinline__ ushort f2b(float f) {   // f32 -> bf16 RNE
    unsigned u = __float_as_uint(f);
    u += 0x7fffu + ((u >> 16) & 1u);
    return (ushort)(u >> 16);
}

// ===================== ws layout (bytes) =====================
// A1: [160][128]  row FFT fwd        @ 0        (40960)
// A2: [256][256]  col FFT fwd        @ 40960    (131072)
// A4: [256][256]  col FFT inv /128   @ 172032   (131072)
// A5: [128][160]  c2r inv /128       @ 303104   (40960)
// WvRe/WvIm: [3][65][64][64]         @ 344064   (2x 1597440)
// XsRe/XsIm: [256*65][128]           @ 12058624 (2x 4259840)
// Zre/Zim:   [256*65][128]           @ 20578304 (2x 4259840)

// ---------------- k_pre: DFT matrices + Wv planes (fused) ----------------
__global__ __launch_bounds__(256) void k_pre(const float* __restrict__ w,
                                             ushort* __restrict__ A1,
                                             ushort* __restrict__ A2,
                                             ushort* __restrict__ A4,
                                             ushort* __restrict__ A5,
                                             ushort* __restrict__ WvRe,
                                             ushort* __restrict__ WvIm) {
    int idx = blockIdx.x * 256 + threadIdx.x;
    if (idx < 20480) {                       // A1[m][k]: m=part*80+v
        int m = idx >> 7, k = idx & 127;
        int part = m / 80, v = m - part * 80;
        float s, c;
        __sincosf(2.f * PI_F * (float)((v * k) & 127) / 128.f, &s, &c);
        float val = (v < 65) ? (part ? -s : c) : 0.f;
        A1[idx] = f2b(val);
    } else if (idx < 86016) {                // A2[m][k2]: fwd col DFT
        int j = idx - 20480;
        int m = j >> 8, k2 = j & 255;
        int part = m >> 7, u = m & 127;
        int kp = k2 >> 7, h = k2 & 127;
        float s, c;
        __sincosf(2.f * PI_F * (float)((u * h) & 127) / 128.f, &s, &c);
        float val = part == 0 ? (kp == 0 ? c : s) : (kp == 0 ? -s : c);
        A2[j] = f2b(val);
    } else if (idx < 151552) {               // A4[m][k2]: inv col DFT, /128
        int j = idx - 86016;
        int m = j >> 8, k2 = j & 255;
        int part = m >> 7, h = m & 127;
        int kp = k2 >> 7, u = k2 & 127;
        float s, c;
        __sincosf(2.f * PI_F * (float)((u * h) & 127) / 128.f, &s, &c);
        float val = part == 0 ? (kp == 0 ? c : -s) : (kp == 0 ? s : c);
        A4[j] = f2b(val * (1.f / 128.f));
    } else if (idx < 172032) {               // A5[x][k2]: c2r, /128
        int j = idx - 151552;
        int x = j / 160, k2 = j - x * 160;
        int part = k2 / 80, v = k2 - part * 80;
        float s, c;
        __sincosf(2.f * PI_F * (float)((v * x) & 127) / 128.f, &s, &c);
        float cv = (v == 0 || v == 64) ? 1.f : 2.f;
        float val = (v < 65) ? (part == 0 ? cv * c : -cv * s) * (1.f / 128.f) : 0.f;
        A5[j] = f2b(val);
    } else {                                 // Wv[p][v][o][i]
        int xw = idx - 172032;               // 0..798719
        int i = xw & 63;
        int o = (xw >> 6) & 63;
        int pv = xw >> 12;
        int p = pv / WF;
        int v = pv % WF;
        const float* wp = w + ((size_t)o * 64 + i) * 9 + p * 3;
        float re = wp[0], im = 0.f;
#pragma unroll
        for (int q = 1; q <= 2; ++q) {
            int k = (v * q) & 127;
            float s, c;
            __sincosf(-2.f * PI_F * (float)k / 128.f, &s, &c);
            re += wp[q] * c;
            im += wp[q] * s;
        }
        WvRe[xw] = f2b(re);
        WvIm[xw] = f2b(im);
    }
}

// ---------------- k_fwd: per-img S1(row rfft) + S2(col DFT+shift+mask), fused ----------
// 512 threads. LDS: B1[h=128][x] pitch 136; B2[v=80][(part,h)=256] pitch 280.
#define B1P 136
#define B2P 280
__global__ __launch_bounds__(512) void k_fwd(const float* __restrict__ x,
                                             const ushort* __restrict__ A1,
                                             const ushort* __restrict__ A2,
                                             ushort* __restrict__ XsRe,
                                             ushort* __restrict__ XsIm) {
    __shared__ ushort B1[128 * B1P];         // 34.8 KB
    __shared__ ushort B2[80 * B2P];          // 44.8 KB
    int t = threadIdx.x;
    int img = blockIdx.x;
    const float* gx = x + (size_t)img * 16384;
    for (int c = t; c < 2048; c += 512) {    // stage x -> bf16 [h][x]
        int r = c >> 4, sl = c & 15;
        const float* src = gx + r * 128 + sl * 8;
        float4 f0 = *(const float4*)src;
        float4 f1 = *(const float4*)(src + 4);
        short8 v8;
        v8[0] = (short)f2b(f0.x); v8[1] = (short)f2b(f0.y);
        v8[2] = (short)f2b(f0.z); v8[3] = (short)f2b(f0.w);
        v8[4] = (short)f2b(f1.x); v8[5] = (short)f2b(f1.y);
        v8[6] = (short)f2b(f1.z); v8[7] = (short)f2b(f1.w);
        *(short8*)&B1[r * B1P + sl * 8] = v8;
    }
    __syncthreads();
    int lane = t & 63, wave = t >> 6;
    int lrow = lane & 15, lq = lane >> 4;

    // ---- S1: C[m=(part,v)][n=h]; wave owns n-tile = wave ----
    {
        f32x4 acc[10];
#pragma unroll
        for (int mt = 0; mt < 10; ++mt) acc[mt] = (f32x4){0.f, 0.f, 0.f, 0.f};
        int hrow = wave * 16 + lrow;
#pragma unroll
        for (int ks = 0; ks < 4; ++ks) {
            short8 b = *(short8*)&B1[hrow * B1P + ks * 32 + lq * 8];
#pragma unroll
            for (int mt = 0; mt < 10; ++mt) {
                short8 a = *(const short8*)&A1[(mt * 16 + lrow) * 128 + ks * 32 + lq * 8];
                acc[mt] = __builtin_amdgcn_mfma_f32_16x16x32_bf16(a, b, acc[mt], 0, 0, 0);
            }
        }
        // write C -> B2[v][part*128 + h]
#pragma unroll
        for (int mt = 0; mt < 10; ++mt) {
            int m0 = mt * 16 + lq * 4;
            int part = m0 >= 80;
            int v0 = m0 - part * 80;
#pragma unroll
            for (int e = 0; e < 4; ++e)
                B2[(v0 + e) * B2P + part * 128 + wave * 16 + lrow] = f2b(acc[mt][e]);
        }
    }
    __syncthreads();

    // ---- S2 (swapped operands): C[m=v][n=(part,u)]; wave owns n-tiles wave*2..+1 ----
    {
        f32x4 acc[5][2];
#pragma unroll
        for (int mt = 0; mt < 5; ++mt)
#pragma unroll
            for (int j = 0; j < 2; ++j) acc[mt][j] = (f32x4){0.f, 0.f, 0.f, 0.f};
#pragma unroll
        for (int ks = 0; ks < 8; ++ks) {
            short8 a[5];
#pragma unroll
            for (int mt = 0; mt < 5; ++mt)
                a[mt] = *(short8*)&B2[(mt * 16 + lrow) * B2P + ks * 32 + lq * 8];
#pragma unroll
            for (int j = 0; j < 2; ++j) {
                int nt = wave * 2 + j;
                short8 b = *(const short8*)&A2[(nt * 16 + lrow) * 256 + ks * 32 + lq * 8];
#pragma unroll
                for (int mt = 0; mt < 5; ++mt)
                    acc[mt][j] = __builtin_amdgcn_mfma_f32_16x16x32_bf16(a[mt], b, acc[mt][j], 0, 0, 0);
            }
        }
#pragma unroll
        for (int j = 0; j < 2; ++j) {
            int nt = wave * 2 + j;
            int part = nt >= 8;
            int u = (nt & 7) * 16 + lrow;
            int u_out = (u + 64) & 127;
            int du = u_out - 64;
            ushort* dimg = (part ? XsIm : XsRe) + (size_t)img * CPLX_PER_IMG;
#pragma unroll
            for (int mt = 0; mt < 5; ++mt)
#pragma unroll
                for (int e = 0; e < 4; ++e) {
                    int v_in = mt * 16 + lq * 4 + e;
                    if (v_in < 65) {
                        int v_out = v_in + 32; if (v_out >= 65) v_out -= 65;
                        int dv = v_out - 64;
                        bool keep = (du * du + dv * dv) > 900;
                        dimg[v_out * 128 + u_out] = keep ? f2b(acc[mt][j][e]) : (ushort)0;
                    }
                }
        }
    }
}

// ---------------- k_gemm: per-(v,b) complex GEMM via bf16 MFMA + phase fold (unchanged) --
#define AP 72
__global__ __launch_bounds__(256, 2) void k_gemm(const ushort* __restrict__ XsRe,
                                                 const ushort* __restrict__ XsIm,
                                                 const ushort* __restrict__ WvRe,
                                                 const ushort* __restrict__ WvIm,
                                                 ushort* __restrict__ Zre,
                                                 ushort* __restrict__ Zim) {
    __shared__ ushort XTre[128 * AP], XTim[128 * AP];
    __shared__ ushort WSre[64 * AP],  WSim[64 * AP];
    int t = threadIdx.x;
    int v = blockIdx.x >> 2;
    int b = blockIdx.x & 3;
    {
        int u = t & 127, qh = t >> 7;
#pragma unroll
        for (int q8 = 0; q8 < 8; ++q8) {
            int q = qh * 8 + q8;
            ushort re4[4], im4[4];
#pragma unroll
            for (int c = 0; c < 4; ++c) {
                int i = q * 4 + c;
                size_t off = ((size_t)(b * 64 + i) * WF + v) * 128 + u;
                re4[c] = XsRe[off];
                im4[c] = XsIm[off];
            }
            *(ushort4*)&XTre[u * AP + q * 4] = make_ushort4(re4[0], re4[1], re4[2], re4[3]);
            *(ushort4*)&XTim[u * AP + q * 4] = make_ushort4(im4[0], im4[1], im4[2], im4[3]);
        }
    }
    int lane = t & 63, wave = t >> 6;
    int lrow = lane & 15, lq = lane >> 4;
    int u0 = wave * 32;
    f32x4 fRe[8], fIm[8];
#pragma unroll
    for (int m = 0; m < 8; ++m) {
        fRe[m] = (f32x4){0.f, 0.f, 0.f, 0.f};
        fIm[m] = (f32x4){0.f, 0.f, 0.f, 0.f};
    }
    for (int p = 0; p < 3; ++p) {
        if (p) __syncthreads();
        {
            const ushort* gr = WvRe + ((size_t)(p * WF + v)) * 4096;
            const ushort* gi = WvIm + ((size_t)(p * WF + v)) * 4096;
#pragma unroll
            for (int cc = 0; cc < 2; ++cc) {
                int c = t + cc * 256;
                int o = c >> 3, i0 = (c & 7) * 8;
                *(short8*)&WSre[o * AP + i0] = *(const short8*)&gr[c * 8];
                *(short8*)&WSim[o * AP + i0] = *(const short8*)&gi[c * 8];
            }
        }
        __syncthreads();
        f32x4 pRe[8], pIm[8];
#pragma unroll
        for (int m = 0; m < 8; ++m) {
            pRe[m] = (f32x4){0.f, 0.f, 0.f, 0.f};
            pIm[m] = (f32x4){0.f, 0.f, 0.f, 0.f};
        }
#pragma unroll
        for (int ks = 0; ks < 2; ++ks) {
            int kb = ks * 32 + lq * 8;
            short8 br[2], bi[2], bin[2];
#pragma unroll
            for (int ut = 0; ut < 2; ++ut) {
                int u = u0 + ut * 16 + lrow;
                br[ut] = *(const short8*)&XTre[u * AP + kb];
                bi[ut] = *(const short8*)&XTim[u * AP + kb];
                bin[ut] = bi[ut] ^ (short)0x8000;
            }
#pragma unroll
            for (int ot = 0; ot < 4; ++ot) {
                int o = ot * 16 + lrow;
                short8 ar = *(const short8*)&WSre[o * AP + kb];
                short8 ai = *(const short8*)&WSim[o * AP + kb];
#pragma unroll
                for (int ut = 0; ut < 2; ++ut) {
                    int m = ot * 2 + ut;
                    pRe[m] = __builtin_amdgcn_mfma_f32_16x16x32_bf16(ai, bin[ut], pRe[m], 0, 0, 0);
                    pRe[m] = __builtin_amdgcn_mfma_f32_16x16x32_bf16(ar, br[ut],  pRe[m], 0, 0, 0);
                    pIm[m] = __builtin_amdgcn_mfma_f32_16x16x32_bf16(ai, br[ut],  pIm[m], 0, 0, 0);
                    pIm[m] = __builtin_amdgcn_mfma_f32_16x16x32_bf16(ar, bi[ut],  pIm[m], 0, 0, 0);
                }
            }
        }
#pragma unroll
        for (int ut = 0; ut < 2; ++ut) {
            int u = u0 + ut * 16 + lrow;
            float sn, cn;
            __sincosf(-2.f * PI_F * (float)(u * p) / 128.f, &sn, &cn);
#pragma unroll
            for (int ot = 0; ot < 4; ++ot) {
                int m = ot * 2 + ut;
#pragma unroll
                for (int e = 0; e < 4; ++e) {
                    fRe[m][e] += pRe[m][e] * cn - pIm[m][e] * sn;
                    fIm[m][e] += pIm[m][e] * cn + pRe[m][e] * sn;
                }
            }
        }
    }
#pragma unroll
    for (int ot = 0; ot < 4; ++ot)
#pragma unroll
        for (int ut = 0; ut < 2; ++ut) {
            int m = ot * 2 + ut;
            int u = u0 + ut * 16 + lrow;
#pragma unroll
            for (int e = 0; e < 4; ++e) {
                int o = ot * 16 + lq * 4 + e;
                size_t idx = ((size_t)(b * 64 + o) * 65 + v) * 128 + u;
                Zre[idx] = f2b(fRe[m][e]);
                Zim[idx] = f2b(fIm[m][e]);
            }
        }
}

// ---------------- k_inv: per-ch S4(col inv DFT) + S5(c2r + bias), fused ----------------
// 512 threads. LDS: B1[v=80][(kp,u)=256] pitch 280; B2[h=128][(part,v)=160] pitch 168.
#define B3P 168
__global__ __launch_bounds__(512) void k_inv(const ushort* __restrict__ Zre,
                                             const ushort* __restrict__ Zim,
                                             const ushort* __restrict__ A4,
                                             const ushort* __restrict__ A5,
                                             const float* __restrict__ bias,
                                             float* __restrict__ out) {
    __shared__ ushort B1[80 * B2P];          // 44.8 KB
    __shared__ ushort B2[128 * B3P];         // 43.0 KB
    int t = threadIdx.x;
    int ch = blockIdx.x;
    for (int c = t; c < 2080; c += 512) {    // stage Z -> [v][kp*128+u]
        int r = c >> 5, sl = c & 31;
        const ushort* src = (sl < 16 ? Zre : Zim) + ((size_t)ch * 65 + r) * 128 + (sl & 15) * 8;
        *(short8*)&B1[r * B2P + sl * 8] = *(const short8*)src;
    }
    if (t < 480) {                           // zero pad rows v=65..79
        int r = 65 + (t >> 5), sl = t & 31;
        short8 z = {0, 0, 0, 0, 0, 0, 0, 0};
        *(short8*)&B1[r * B2P + sl * 8] = z;
    }
    __syncthreads();
    int lane = t & 63, wave = t >> 6;
    int lrow = lane & 15, lq = lane >> 4;

    // ---- S4: C[m=(part,h)][n=v]; wave owns m-tiles wave*2..+1 ----
    {
        f32x4 acc[2][5];
#pragma unroll
        for (int m2 = 0; m2 < 2; ++m2)
#pragma unroll
            for (int nt = 0; nt < 5; ++nt) acc[m2][nt] = (f32x4){0.f, 0.f, 0.f, 0.f};
#pragma unroll
        for (int ks = 0; ks < 8; ++ks) {
            short8 b[5];
#pragma unroll
            for (int nt = 0; nt < 5; ++nt)
                b[nt] = *(short8*)&B1[(nt * 16 + lrow) * B2P + ks * 32 + lq * 8];
#pragma unroll
            for (int m2 = 0; m2 < 2; ++m2) {
                int mt = wave * 2 + m2;
                short8 a = *(const short8*)&A4[(mt * 16 + lrow) * 256 + ks * 32 + lq * 8];
#pragma unroll
                for (int nt = 0; nt < 5; ++nt)
                    acc[m2][nt] = __builtin_amdgcn_mfma_f32_16x16x32_bf16(a, b[nt], acc[m2][nt], 0, 0, 0);
            }
        }
        // write C -> B2[h][part*80 + v]
#pragma unroll
        for (int m2 = 0; m2 < 2; ++m2) {
            int mt = wave * 2 + m2;
            int part = mt >= 8;
            int h0 = mt * 16 + lq * 4 - part * 128;
#pragma unroll
            for (int nt = 0; nt < 5; ++nt) {
                int v = nt * 16 + lrow;
#pragma unroll
                for (int e = 0; e < 4; ++e)
                    B2[(h0 + e) * B3P + part * 80 + v] = f2b(acc[m2][nt][e]);
            }
        }
    }
    __syncthreads();

    // ---- S5 (swapped operands): C[m=h][n=x]; wave owns m-tile = wave ----
    {
        f32x4 acc[8];
#pragma unroll
        for (int nt = 0; nt < 8; ++nt) acc[nt] = (f32x4){0.f, 0.f, 0.f, 0.f};
#pragma unroll
        for (int ks = 0; ks < 5; ++ks) {
            short8 a = *(short8*)&B2[(wave * 16 + lrow) * B3P + ks * 32 + lq * 8];
#pragma unroll
            for (int nt = 0; nt < 8; ++nt) {
                short8 b = *(const short8*)&A5[(nt * 16 + lrow) * 160 + ks * 32 + lq * 8];
                acc[nt] = __builtin_amdgcn_mfma_f32_16x16x32_bf16(a, b, acc[nt], 0, 0, 0);
            }
        }
        float bo = bias[ch & 63];
        float* go = out + (size_t)ch * 16384;
#pragma unroll
        for (int nt = 0; nt < 8; ++nt) {
            int xx = nt * 16 + lrow;
#pragma unroll
            for (int e = 0; e < 4; ++e) {
                int h = wave * 16 + lq * 4 + e;
                go[h * 128 + xx] = acc[nt][e] + bo;
            }
        }
    }
}

extern "C" void kernel_launch(void* const* d_in, const int* in_sizes, int n_in,
                              void* d_out, int out_size, void* d_ws, size_t ws_size,
                              hipStream_t stream) {
    const float* x = (const float*)d_in[0];      // [4,64,128,128]
    const float* w = (const float*)d_in[1];      // [64,64,3,3]
    const float* bias = (const float*)d_in[2];   // [64]
    float* out = (float*)d_out;                  // [4,64,128,128]

    char* ws = (char*)d_ws;
    ushort* A1   = (ushort*)(ws + 0);
    ushort* A2   = (ushort*)(ws + 40960);
    ushort* A4   = (ushort*)(ws + 172032);
    ushort* A5   = (ushort*)(ws + 303104);
    ushort* WvRe = (ushort*)(ws + 344064);
    ushort* WvIm = (ushort*)(ws + 1941504);
    ushort* XsRe = (ushort*)(ws + 12058624);
    ushort* XsIm = (ushort*)(ws + 16318464);
    ushort* Zre  = (ushort*)(ws + 20578304);
    ushort* Zim  = (ushort*)(ws + 24838144);

    k_pre<<<3792, 256, 0, stream>>>(w, A1, A2, A4, A5, WvRe, WvIm);
    k_fwd<<<NB * NC, 512, 0, stream>>>(x, A1, A2, XsRe, XsIm);
    k_gemm<<<WF * NB, 256, 0, stream>>>(XsRe, XsIm, WvRe, WvIm, Zre, Zim);
    k_inv<<<NB * NC, 512, 0, stream>>>(Zre, Zim, A4, A5, bias, out);
}

// Round 8
// 54.212 us; speedup vs baseline: 15.9719x; 1.0171x over previous
//
#include <hip/hip_runtime.h>

#define PI_F 3.14159265358979323846f

// Problem constants: B=4, Cin=Cout=64, H=W=128, Wf=65, K=3
#define HH 128
#define WW 128
#define WF 65
#define NB 4
#define NC 64
#define CPLX_PER_IMG (HH * WF)                  // 8320

typedef __attribute__((ext_vector_type(8))) short short8;
typedef __attribute__((ext_vector_type(4))) float f32x4;

__device__ __forceinline__ ushort f2b(float f) {   // f32 -> bf16 RNE
    unsigned u = __float_as_uint(f);
    u += 0x7fffu + ((u >> 16) & 1u);
    return (ushort)(u >> 16);
}

// ===================== ws layout (bytes) =====================
// A1: [160][128]  row FFT fwd        @ 0        (40960)
// A2: [256][256]  col FFT fwd        @ 40960    (131072)
// A4: [256][256]  col FFT inv /128   @ 172032   (131072)
// A5: [128][160]  c2r inv /128       @ 303104   (40960)
// WvRe/WvIm: [3][65][64][64]         @ 344064   (2x 1597440)
// XsRe/XsIm: [256*65][128]           @ 12058624 (2x 4259840)
// Zre/Zim:   [256*65][128]           @ 20578304 (2x 4259840)

// ---------------- k_pre: DFT matrices + Wv planes (fused) ----------------
__global__ __launch_bounds__(256) void k_pre(const float* __restrict__ w,
                                             ushort* __restrict__ A1,
                                             ushort* __restrict__ A2,
                                             ushort* __restrict__ A4,
                                             ushort* __restrict__ A5,
                                             ushort* __restrict__ WvRe,
                                             ushort* __restrict__ WvIm) {
    int idx = blockIdx.x * 256 + threadIdx.x;
    if (idx < 20480) {                       // A1[m][k]: m=part*80+v
        int m = idx >> 7, k = idx & 127;
        int part = m / 80, v = m - part * 80;
        float s, c;
        __sincosf(2.f * PI_F * (float)((v * k) & 127) / 128.f, &s, &c);
        float val = (v < 65) ? (part ? -s : c) : 0.f;
        A1[idx] = f2b(val);
    } else if (idx < 86016) {                // A2[m][k2]: fwd col DFT
        int j = idx - 20480;
        int m = j >> 8, k2 = j & 255;
        int part = m >> 7, u = m & 127;
        int kp = k2 >> 7, h = k2 & 127;
        float s, c;
        __sincosf(2.f * PI_F * (float)((u * h) & 127) / 128.f, &s, &c);
        float val = part == 0 ? (kp == 0 ? c : s) : (kp == 0 ? -s : c);
        A2[j] = f2b(val);
    } else if (idx < 151552) {               // A4[m][k2]: inv col DFT, /128
        int j = idx - 86016;
        int m = j >> 8, k2 = j & 255;
        int part = m >> 7, h = m & 127;
        int kp = k2 >> 7, u = k2 & 127;
        float s, c;
        __sincosf(2.f * PI_F * (float)((u * h) & 127) / 128.f, &s, &c);
        float val = part == 0 ? (kp == 0 ? c : -s) : (kp == 0 ? s : c);
        A4[j] = f2b(val * (1.f / 128.f));
    } else if (idx < 172032) {               // A5[x][k2]: c2r, /128
        int j = idx - 151552;
        int x = j / 160, k2 = j - x * 160;
        int part = k2 / 80, v = k2 - part * 80;
        float s, c;
        __sincosf(2.f * PI_F * (float)((v * x) & 127) / 128.f, &s, &c);
        float cv = (v == 0 || v == 64) ? 1.f : 2.f;
        float val = (v < 65) ? (part == 0 ? cv * c : -cv * s) * (1.f / 128.f) : 0.f;
        A5[j] = f2b(val);
    } else {                                 // Wv[p][v][o][i]
        int xw = idx - 172032;               // 0..798719
        int i = xw & 63;
        int o = (xw >> 6) & 63;
        int pv = xw >> 12;
        int p = pv / WF;
        int v = pv % WF;
        const float* wp = w + ((size_t)o * 64 + i) * 9 + p * 3;
        float re = wp[0], im = 0.f;
#pragma unroll
        for (int q = 1; q <= 2; ++q) {
            int k = (v * q) & 127;
            float s, c;
            __sincosf(-2.f * PI_F * (float)k / 128.f, &s, &c);
            re += wp[q] * c;
            im += wp[q] * s;
        }
        WvRe[xw] = f2b(re);
        WvIm[xw] = f2b(im);
    }
}

// ---------------- k_fwd: per-img S1(row rfft) + S2(col DFT+shift+mask), fused ----------
// 1024 threads (16 waves). LDS: B1[h=128][x] pitch 136; B2[v=80][(part,h)=256] pitch 280.
#define B1P 136
#define B2P 280
__global__ __launch_bounds__(1024) void k_fwd(const float* __restrict__ x,
                                              const ushort* __restrict__ A1,
                                              const ushort* __restrict__ A2,
                                              ushort* __restrict__ XsRe,
                                              ushort* __restrict__ XsIm) {
    __shared__ ushort B1[128 * B1P];         // 34.8 KB
    __shared__ ushort B2[80 * B2P];          // 44.8 KB
    int t = threadIdx.x;
    int img = blockIdx.x;
    const float* gx = x + (size_t)img * 16384;
    for (int c = t; c < 2048; c += 1024) {   // stage x -> bf16 [h][x]
        int r = c >> 4, sl = c & 15;
        const float* src = gx + r * 128 + sl * 8;
        float4 f0 = *(const float4*)src;
        float4 f1 = *(const float4*)(src + 4);
        short8 v8;
        v8[0] = (short)f2b(f0.x); v8[1] = (short)f2b(f0.y);
        v8[2] = (short)f2b(f0.z); v8[3] = (short)f2b(f0.w);
        v8[4] = (short)f2b(f1.x); v8[5] = (short)f2b(f1.y);
        v8[6] = (short)f2b(f1.z); v8[7] = (short)f2b(f1.w);
        *(short8*)&B1[r * B1P + sl * 8] = v8;
    }
    __syncthreads();
    int lane = t & 63, wave = t >> 6;        // wave 0..15
    int lrow = lane & 15, lq = lane >> 4;

    // ---- S1: C[m=(part,v)][n=h]; wave (g=w>>3, nt=w&7): 5 m-tiles x 1 h-tile ----
    {
        int g = wave >> 3, nt = wave & 7;
        int hrow = nt * 16 + lrow;
        f32x4 acc[5];
#pragma unroll
        for (int j = 0; j < 5; ++j) acc[j] = (f32x4){0.f, 0.f, 0.f, 0.f};
#pragma unroll
        for (int ks = 0; ks < 4; ++ks) {
            short8 b = *(short8*)&B1[hrow * B1P + ks * 32 + lq * 8];
#pragma unroll
            for (int j = 0; j < 5; ++j) {
                int mt = g * 5 + j;
                short8 a = *(const short8*)&A1[(mt * 16 + lrow) * 128 + ks * 32 + lq * 8];
                acc[j] = __builtin_amdgcn_mfma_f32_16x16x32_bf16(a, b, acc[j], 0, 0, 0);
            }
        }
        // write C -> B2[v][part*128 + h]
#pragma unroll
        for (int j = 0; j < 5; ++j) {
            int m0 = (g * 5 + j) * 16 + lq * 4;
            int part = m0 >= 80;
            int v0 = m0 - part * 80;
#pragma unroll
            for (int e = 0; e < 4; ++e)
                B2[(v0 + e) * B2P + part * 128 + hrow] = f2b(acc[j][e]);
        }
    }
    __syncthreads();

    // ---- S2 (swapped operands): C[m=v][n=(part,u)]; wave owns n-tile = wave ----
    {
        int nt = wave;
        f32x4 acc[5];
#pragma unroll
        for (int mt = 0; mt < 5; ++mt) acc[mt] = (f32x4){0.f, 0.f, 0.f, 0.f};
#pragma unroll
        for (int ks = 0; ks < 8; ++ks) {
            short8 b = *(const short8*)&A2[(nt * 16 + lrow) * 256 + ks * 32 + lq * 8];
#pragma unroll
            for (int mt = 0; mt < 5; ++mt) {
                short8 a = *(short8*)&B2[(mt * 16 + lrow) * B2P + ks * 32 + lq * 8];
                acc[mt] = __builtin_amdgcn_mfma_f32_16x16x32_bf16(a, b, acc[mt], 0, 0, 0);
            }
        }
        int part = nt >= 8;
        int u = (nt & 7) * 16 + lrow;
        int u_out = (u + 64) & 127;
        int du = u_out - 64;
        ushort* dimg = (part ? XsIm : XsRe) + (size_t)img * CPLX_PER_IMG;
#pragma unroll
        for (int mt = 0; mt < 5; ++mt)
#pragma unroll
            for (int e = 0; e < 4; ++e) {
                int v_in = mt * 16 + lq * 4 + e;
                if (v_in < 65) {
                    int v_out = v_in + 32; if (v_out >= 65) v_out -= 65;
                    int dv = v_out - 64;
                    bool keep = (du * du + dv * dv) > 900;
                    dimg[v_out * 128 + u_out] = keep ? f2b(acc[mt][e]) : (ushort)0;
                }
            }
    }
}

// ---------------- k_gemm: per-(v,b) complex GEMM via bf16 MFMA + phase fold (unchanged) --
#define AP 72
__global__ __launch_bounds__(256, 2) void k_gemm(const ushort* __restrict__ XsRe,
                                                 const ushort* __restrict__ XsIm,
                                                 const ushort* __restrict__ WvRe,
                                                 const ushort* __restrict__ WvIm,
                                                 ushort* __restrict__ Zre,
                                                 ushort* __restrict__ Zim) {
    __shared__ ushort XTre[128 * AP], XTim[128 * AP];
    __shared__ ushort WSre[64 * AP],  WSim[64 * AP];
    int t = threadIdx.x;
    int v = blockIdx.x >> 2;
    int b = blockIdx.x & 3;
    {
        int u = t & 127, qh = t >> 7;
#pragma unroll
        for (int q8 = 0; q8 < 8; ++q8) {
            int q = qh * 8 + q8;
            ushort re4[4], im4[4];
#pragma unroll
            for (int c = 0; c < 4; ++c) {
                int i = q * 4 + c;
                size_t off = ((size_t)(b * 64 + i) * WF + v) * 128 + u;
                re4[c] = XsRe[off];
                im4[c] = XsIm[off];
            }
            *(ushort4*)&XTre[u * AP + q * 4] = make_ushort4(re4[0], re4[1], re4[2], re4[3]);
            *(ushort4*)&XTim[u * AP + q * 4] = make_ushort4(im4[0], im4[1], im4[2], im4[3]);
        }
    }
    int lane = t & 63, wave = t >> 6;
    int lrow = lane & 15, lq = lane >> 4;
    int u0 = wave * 32;
    f32x4 fRe[8], fIm[8];
#pragma unroll
    for (int m = 0; m < 8; ++m) {
        fRe[m] = (f32x4){0.f, 0.f, 0.f, 0.f};
        fIm[m] = (f32x4){0.f, 0.f, 0.f, 0.f};
    }
    for (int p = 0; p < 3; ++p) {
        if (p) __syncthreads();
        {
            const ushort* gr = WvRe + ((size_t)(p * WF + v)) * 4096;
            const ushort* gi = WvIm + ((size_t)(p * WF + v)) * 4096;
#pragma unroll
            for (int cc = 0; cc < 2; ++cc) {
                int c = t + cc * 256;
                int o = c >> 3, i0 = (c & 7) * 8;
                *(short8*)&WSre[o * AP + i0] = *(const short8*)&gr[c * 8];
                *(short8*)&WSim[o * AP + i0] = *(const short8*)&gi[c * 8];
            }
        }
        __syncthreads();
        f32x4 pRe[8], pIm[8];
#pragma unroll
        for (int m = 0; m < 8; ++m) {
            pRe[m] = (f32x4){0.f, 0.f, 0.f, 0.f};
            pIm[m] = (f32x4){0.f, 0.f, 0.f, 0.f};
        }
#pragma unroll
        for (int ks = 0; ks < 2; ++ks) {
            int kb = ks * 32 + lq * 8;
            short8 br[2], bi[2], bin[2];
#pragma unroll
            for (int ut = 0; ut < 2; ++ut) {
                int u = u0 + ut * 16 + lrow;
                br[ut] = *(const short8*)&XTre[u * AP + kb];
                bi[ut] = *(const short8*)&XTim[u * AP + kb];
                bin[ut] = bi[ut] ^ (short)0x8000;
            }
#pragma unroll
            for (int ot = 0; ot < 4; ++ot) {
                int o = ot * 16 + lrow;
                short8 ar = *(const short8*)&WSre[o * AP + kb];
                short8 ai = *(const short8*)&WSim[o * AP + kb];
#pragma unroll
                for (int ut = 0; ut < 2; ++ut) {
                    int m = ot * 2 + ut;
                    pRe[m] = __builtin_amdgcn_mfma_f32_16x16x32_bf16(ai, bin[ut], pRe[m], 0, 0, 0);
                    pRe[m] = __builtin_amdgcn_mfma_f32_16x16x32_bf16(ar, br[ut],  pRe[m], 0, 0, 0);
                    pIm[m] = __builtin_amdgcn_mfma_f32_16x16x32_bf16(ai, br[ut],  pIm[m], 0, 0, 0);
                    pIm[m] = __builtin_amdgcn_mfma_f32_16x16x32_bf16(ar, bi[ut],  pIm[m], 0, 0, 0);
                }
            }
        }
#pragma unroll
        for (int ut = 0; ut < 2; ++ut) {
            int u = u0 + ut * 16 + lrow;
            float sn, cn;
            __sincosf(-2.f * PI_F * (float)(u * p) / 128.f, &sn, &cn);
#pragma unroll
            for (int ot = 0; ot < 4; ++ot) {
                int m = ot * 2 + ut;
#pragma unroll
                for (int e = 0; e < 4; ++e) {
                    fRe[m][e] += pRe[m][e] * cn - pIm[m][e] * sn;
                    fIm[m][e] += pIm[m][e] * cn + pRe[m][e] * sn;
                }
            }
        }
    }
#pragma unroll
    for (int ot = 0; ot < 4; ++ot)
#pragma unroll
        for (int ut = 0; ut < 2; ++ut) {
            int m = ot * 2 + ut;
            int u = u0 + ut * 16 + lrow;
#pragma unroll
            for (int e = 0; e < 4; ++e) {
                int o = ot * 16 + lq * 4 + e;
                size_t idx = ((size_t)(b * 64 + o) * 65 + v) * 128 + u;
                Zre[idx] = f2b(fRe[m][e]);
                Zim[idx] = f2b(fIm[m][e]);
            }
        }
}

// ---------------- k_inv: per-ch S4(col inv DFT) + S5(c2r + bias), fused ----------------
// 1024 threads (16 waves). LDS: B1[v=80][(kp,u)=256] pitch 280; B2[h=128][(part,v)=160] pitch 168.
#define B3P 168
__global__ __launch_bounds__(1024) void k_inv(const ushort* __restrict__ Zre,
                                              const ushort* __restrict__ Zim,
                                              const ushort* __restrict__ A4,
                                              const ushort* __restrict__ A5,
                                              const float* __restrict__ bias,
                                              float* __restrict__ out) {
    __shared__ ushort B1[80 * B2P];          // 44.8 KB
    __shared__ ushort B2[128 * B3P];         // 43.0 KB
    int t = threadIdx.x;
    int ch = blockIdx.x;
    for (int c = t; c < 2080; c += 1024) {   // stage Z -> [v][kp*128+u]
        int r = c >> 5, sl = c & 31;
        const ushort* src = (sl < 16 ? Zre : Zim) + ((size_t)ch * 65 + r) * 128 + (sl & 15) * 8;
        *(short8*)&B1[r * B2P + sl * 8] = *(const short8*)src;
    }
    if (t < 480) {                           // zero pad rows v=65..79
        int r = 65 + (t >> 5), sl = t & 31;
        short8 z = {0, 0, 0, 0, 0, 0, 0, 0};
        *(short8*)&B1[r * B2P + sl * 8] = z;
    }
    __syncthreads();
    int lane = t & 63, wave = t >> 6;        // wave 0..15
    int lrow = lane & 15, lq = lane >> 4;

    // ---- S4: C[m=(part,h)][n=v]; wave owns m-tile = wave, all 5 n-tiles ----
    {
        int mt = wave;
        f32x4 acc[5];
#pragma unroll
        for (int nt = 0; nt < 5; ++nt) acc[nt] = (f32x4){0.f, 0.f, 0.f, 0.f};
#pragma unroll
        for (int ks = 0; ks < 8; ++ks) {
            short8 a = *(const short8*)&A4[(mt * 16 + lrow) * 256 + ks * 32 + lq * 8];
#pragma unroll
            for (int nt = 0; nt < 5; ++nt) {
                short8 b = *(short8*)&B1[(nt * 16 + lrow) * B2P + ks * 32 + lq * 8];
                acc[nt] = __builtin_amdgcn_mfma_f32_16x16x32_bf16(a, b, acc[nt], 0, 0, 0);
            }
        }
        // write C -> B2[h][part*80 + v]
        int part = mt >= 8;
        int h0 = mt * 16 + lq * 4 - part * 128;
#pragma unroll
        for (int nt = 0; nt < 5; ++nt) {
            int v = nt * 16 + lrow;
#pragma unroll
            for (int e = 0; e < 4; ++e)
                B2[(h0 + e) * B3P + part * 80 + v] = f2b(acc[nt][e]);
        }
    }
    __syncthreads();

    // ---- S5 (swapped operands): C[m=h][n=x]; wave (mt=w&7, nh=w>>3): 4 n-tiles ----
    {
        int mt = wave & 7, nh = wave >> 3;
        f32x4 acc[4];
#pragma unroll
        for (int jn = 0; jn < 4; ++jn) acc[jn] = (f32x4){0.f, 0.f, 0.f, 0.f};
#pragma unroll
        for (int ks = 0; ks < 5; ++ks) {
            short8 a = *(short8*)&B2[(mt * 16 + lrow) * B3P + ks * 32 + lq * 8];
#pragma unroll
            for (int jn = 0; jn < 4; ++jn) {
                int nt = nh * 4 + jn;
                short8 b = *(const short8*)&A5[(nt * 16 + lrow) * 160 + ks * 32 + lq * 8];
                acc[jn] = __builtin_amdgcn_mfma_f32_16x16x32_bf16(a, b, acc[jn], 0, 0, 0);
            }
        }
        float bo = bias[ch & 63];
        float* go = out + (size_t)ch * 16384;
#pragma unroll
        for (int jn = 0; jn < 4; ++jn) {
            int xx = (nh * 4 + jn) * 16 + lrow;
#pragma unroll
            for (int e = 0; e < 4; ++e) {
                int h = mt * 16 + lq * 4 + e;
                go[h * 128 + xx] = acc[jn][e] + bo;
            }
        }
    }
}

extern "C" void kernel_launch(void* const* d_in, const int* in_sizes, int n_in,
                              void* d_out, int out_size, void* d_ws, size_t ws_size,
                              hipStream_t stream) {
    const float* x = (const float*)d_in[0];      // [4,64,128,128]
    const float* w = (const float*)d_in[1];      // [64,64,3,3]
    const float* bias = (const float*)d_in[2];   // [64]
    float* out = (float*)d_out;                  // [4,64,128,128]

    char* ws = (char*)d_ws;
    ushort* A1   = (ushort*)(ws + 0);
    ushort* A2   = (ushort*)(ws + 40960);
    ushort* A4   = (ushort*)(ws + 172032);
    ushort* A5   = (ushort*)(ws + 303104);
    ushort* WvRe = (ushort*)(ws + 344064);
    ushort* WvIm = (ushort*)(ws + 1941504);
    ushort* XsRe = (ushort*)(ws + 12058624);
    ushort* XsIm = (ushort*)(ws + 16318464);
    ushort* Zre  = (ushort*)(ws + 20578304);
    ushort* Zim  = (ushort*)(ws + 24838144);

    k_pre<<<3792, 256, 0, stream>>>(w, A1, A2, A4, A5, WvRe, WvIm);
    k_fwd<<<NB * NC, 1024, 0, stream>>>(x, A1, A2, XsRe, XsIm);
    k_gemm<<<WF * NB, 256, 0, stream>>>(XsRe, XsIm, WvRe, WvIm, Zre, Zim);
    k_inv<<<NB * NC, 1024, 0, stream>>>(Zre, Zim, A4, A5, bias, out);
}